// Round 19
// baseline (232.300 us; speedup 1.0000x reference)
//
#include <hip/hip_runtime.h>

#define L_ 256
#define C_ 256
#define H_ 8
#define D_ 32
#define F_ 512
#define M_ (L_*L_)   // 65536 rows
#define SCALE2_ 0.2550348564624926f   // (1/sqrt(32)) * log2(e)
#define LOG2E_  1.4426950408889634f

typedef __attribute__((ext_vector_type(8))) short v8s;    // 8 bf16 = 16B
typedef __attribute__((ext_vector_type(4))) float v4f;    // 16x16 MFMA acc
typedef __attribute__((ext_vector_type(16))) float v16f;  // 32x32 MFMA acc
#define Z16 (v16f){0,0,0,0,0,0,0,0,0,0,0,0,0,0,0,0}

__device__ __forceinline__ ushort f2bf(float f) {
  union { float f; unsigned u; } v; v.f = f;
  unsigned r = v.u + 0x7FFFu + ((v.u >> 16) & 1u);   // RNE
  return (ushort)(r >> 16);
}

__device__ __forceinline__ float bf2f(ushort u) {
  union { unsigned u; float f; } v; v.u = (unsigned)u << 16;
  return v.f;
}

// pack 2 fp32 -> 2 bf16 in one instr (RNE); lo -> bits 0-15
__device__ __forceinline__ uint cvtpk(float lo, float hi) {
  uint r;
  asm("v_cvt_pk_bf16_f32 %0, %1, %2" : "=v"(r) : "v"(lo), "v"(hi));
  return r;
}

__device__ __forceinline__ void gload16(const void* g, void* l) {
  __builtin_amdgcn_global_load_lds(
      (const __attribute__((address_space(1))) void*)g,
      (__attribute__((address_space(3))) void*)l, 16, 0, 0);
}

// half-exchange: a' = [a.lo | b.lo], b' = [a.hi | b.hi]
__device__ __forceinline__ void pl32swap(uint &a, uint &b) {
  asm volatile("v_permlane32_swap_b32 %0, %1" : "+v"(a), "+v"(b));
}

// ---------------- prep: weights -> bf16, bias retile for 32x32 path ----------
// bM4 entries carry the fixed softmax shift: b*log2e - 8 (softmax is
// shift-invariant; bf16/fp32 share exponent range so no stability cost).
__global__ __launch_bounds__(256) void prep_k(
    const float* __restrict__ Wq, const float* __restrict__ Wk,
    const float* __restrict__ Wv, const float* __restrict__ Wo,
    const float* __restrict__ W1, const float* __restrict__ W2,
    const float* __restrict__ bq, const float* __restrict__ bk,
    const float* __restrict__ bv,
    const float* __restrict__ bias, const int* __restrict__ mask,
    ushort* __restrict__ Wqkvb, ushort* __restrict__ Wob,
    ushort* __restrict__ W1b, ushort* __restrict__ W2b,
    float* __restrict__ bqkv, float* __restrict__ bM4) {
  int idx = blockIdx.x * 256 + threadIdx.x;
  if (idx < 49152) {                             // Wqkv: 768x256
    int e = idx * 4; int n = e >> 8; int k = e & 255;
    const float* src = n < 256 ? &Wq[n*256 + k]
                     : n < 512 ? &Wk[(n-256)*256 + k]
                               : &Wv[(n-512)*256 + k];
    float4 f = *(const float4*)src;
    ushort4 o = { f2bf(f.x), f2bf(f.y), f2bf(f.z), f2bf(f.w) };
    *(ushort4*)&Wqkvb[e] = o;
  } else if (idx < 65536) {                      // Wo: 256x256
    int e = (idx - 49152) * 4;
    float4 f = *(const float4*)&Wo[e];
    ushort4 o = { f2bf(f.x), f2bf(f.y), f2bf(f.z), f2bf(f.w) };
    *(ushort4*)&Wob[e] = o;
  } else if (idx < 98304) {                      // W1: 512x256
    int e = (idx - 65536) * 4;
    float4 f = *(const float4*)&W1[e];
    ushort4 o = { f2bf(f.x), f2bf(f.y), f2bf(f.z), f2bf(f.w) };
    *(ushort4*)&W1b[e] = o;
  } else if (idx < 131072) {                     // W2: 256x512
    int e = (idx - 98304) * 4;
    float4 f = *(const float4*)&W2[e];
    ushort4 o = { f2bf(f.x), f2bf(f.y), f2bf(f.z), f2bf(f.w) };
    *(ushort4*)&W2b[e] = o;
  } else if (idx < 262144) {                     // bM4[h][qb][c][h5][r4][q32][j]
    int eb = idx - 131072;
    int q32 = eb & 31, r4 = (eb >> 5) & 3, h5 = (eb >> 7) & 1;
    int c = (eb >> 8) & 7, qb = (eb >> 11) & 7, h = eb >> 14;
    int q = qb*32 + q32;
    int keyb = 32*c + 8*r4 + 4*h5;
    float4 b4 = *(const float4*)&bias[((size_t)(h*256 + q))*256 + keyb];
    int4   m4 = *(const int4*)&mask[(size_t)q*256 + keyb];
    float4 o;
    o.x = m4.x ? b4.x * LOG2E_ - 8.0f : -1e30f;
    o.y = m4.y ? b4.y * LOG2E_ - 8.0f : -1e30f;
    o.z = m4.z ? b4.z * LOG2E_ - 8.0f : -1e30f;
    o.w = m4.w ? b4.w * LOG2E_ - 8.0f : -1e30f;
    *(float4*)&bM4[(size_t)eb*4] = o;
  } else if (idx < 262336) {                     // bqkv: 768
    int e = (idx - 262144) * 4;
    const float* src = e < 256 ? &bq[e] : e < 512 ? &bk[e-256] : &bv[e-512];
    *(float4*)&bqkv[e] = *(const float4*)src;
  }
}

// ---------------- LayerNorm; TR=true writes j-major rows ---------------------
template<bool TR>
__global__ __launch_bounds__(256) void ln_k(const float* __restrict__ in,
    const float* __restrict__ g, const float* __restrict__ b,
    ushort* __restrict__ out) {
  int wid = threadIdx.x >> 6, lane = threadIdx.x & 63;
  size_t row = (size_t)blockIdx.x * 4 + wid;
  const float* x = in + row * C_;
  float4 v = *(const float4*)&x[lane*4];
  float s  = v.x + v.y + v.z + v.w;
  float s2 = v.x*v.x + v.y*v.y + v.z*v.z + v.w*v.w;
  #pragma unroll
  for (int off = 1; off < 64; off <<= 1) {
    s  += __shfl_xor(s,  off);
    s2 += __shfl_xor(s2, off);
  }
  float mean = s * (1.0f/C_);
  float var  = s2 * (1.0f/C_) - mean*mean;
  float inv  = rsqrtf(var + 1e-5f);
  float4 gg = *(const float4*)&g[lane*4];
  float4 bb = *(const float4*)&b[lane*4];
  ushort4 o;
  o.x = f2bf((v.x-mean)*inv*gg.x + bb.x);
  o.y = f2bf((v.y-mean)*inv*gg.y + bb.y);
  o.z = f2bf((v.z-mean)*inv*gg.z + bb.z);
  o.w = f2bf((v.w-mean)*inv*gg.w + bb.w);
  size_t orow = TR ? ((row & 255) * 256 + (row >> 8)) : row;
  *(ushort4*)&out[orow*C_ + lane*4] = o;
}

// ---------------- bf16 MFMA NT GEMM: BK=64, swizzled LDS ---------------------
// bf16 outputs (QKV / plain OUTBF16) go through an LDS-transpose epilogue so
// each lane stores 16B and waves emit full-cache-line runs.
// ADD: fp32 residual; ADDB: bf16 residual. R/Optr NOT restrict-qualified.
template<bool OUTBF16, bool RELU, bool ADD, bool ADDB, bool QKV>
__global__ __launch_bounds__(256) void gemm5(
    const ushort* __restrict__ A, const ushort* __restrict__ W,
    const float* __restrict__ bias, const void* Rp,
    void* Optr, int N, int K, int lda, int ldo, int nby) {
  __shared__ __align__(16) ushort LDSb[2][128][64];   // As=LDSb[0], Bs=LDSb[1]
  constexpr bool LDST = QKV || (OUTBF16 && !ADD && !ADDB);
  int f = blockIdx.x;
  int sw = (f & 7) * (gridDim.x >> 3) + (f >> 3);   // XCD-bijective (grid%8==0)
  const int bm = (sw / nby) * 128;
  const int bn = (sw % nby) * 128;
  const int t  = threadIdx.x;
  const int lane = t & 63, w = t >> 6;
  const int wm = (w >> 1) * 64, wn = (w & 1) * 64;
  const int lg = lane >> 4, lc = lane & 15;
  const int srow0 = t >> 3;          // 0..31
  const int scc   = t & 7;           // 16B chunk index

  v4f acc[4][4];
  #pragma unroll
  for (int i = 0; i < 4; ++i)
    #pragma unroll
    for (int jj = 0; jj < 4; ++jj) acc[i][jj] = (v4f){0.f,0.f,0.f,0.f};

  for (int k0 = 0; k0 < K; k0 += 64) {
    // stage: LDS[row][cc] <- global chunk (cc ^ (row&7))  [involution]
    #pragma unroll
    for (int s = 0; s < 4; ++s) {
      int row = s*32 + srow0;
      int gc  = (scc ^ (row & 7)) * 8;
      gload16(&A[(size_t)(bm + row)*lda + k0 + gc], (char*)LDSb + s*4096 + t*16);
      gload16(&W[(size_t)(bn + row)*K  + k0 + gc], (char*)LDSb + 16384 + s*4096 + t*16);
    }
    __syncthreads();
    #pragma unroll
    for (int kh = 0; kh < 2; ++kh) {
      v8s af[4], bf_[4];
      #pragma unroll
      for (int mi = 0; mi < 4; ++mi) {
        int row = wm + mi*16 + lc;
        int cd  = ((kh*4 + lg) ^ (row & 7)) * 16;
        af[mi] = *(const v8s*)((const char*)LDSb + row*128 + cd);
      }
      #pragma unroll
      for (int ni = 0; ni < 4; ++ni) {
        int row = wn + ni*16 + lc;
        int cd  = ((kh*4 + lg) ^ (row & 7)) * 16;
        bf_[ni] = *(const v8s*)((const char*)LDSb + 16384 + row*128 + cd);
      }
      // swapped operands: D row-index <- W (n), col-index <- A (m)
      #pragma unroll
      for (int mi = 0; mi < 4; ++mi)
        #pragma unroll
        for (int ni = 0; ni < 4; ++ni)
          acc[mi][ni] = __builtin_amdgcn_mfma_f32_16x16x32_bf16(bf_[ni], af[mi], acc[mi][ni], 0, 0, 0);
    }
    __syncthreads();
  }
  // epilogue: lane owns O[m = bm+wm+mi*16+lc][n0 .. n0+3], n0 = bn+wn+ni*16+lg*4
  if (LDST) {
    // stage bf16 tile in LDS (XOR-swizzled), then 16B/lane coalesced stores
    ushort* T = (ushort*)LDSb;   // [128][128]
    #pragma unroll
    for (int mi = 0; mi < 4; ++mi) {
      int row = wm + mi*16 + lc;
      #pragma unroll
      for (int ni = 0; ni < 4; ++ni) {
        int col = wn + ni*16 + lg*4;
        float4 bv = *(const float4*)&bias[bn + col];
        float o0 = acc[mi][ni][0] + bv.x;
        float o1 = acc[mi][ni][1] + bv.y;
        float o2 = acc[mi][ni][2] + bv.z;
        float o3 = acc[mi][ni][3] + bv.w;
        if (RELU) {
          o0 = fmaxf(o0, 0.f); o1 = fmaxf(o1, 0.f);
          o2 = fmaxf(o2, 0.f); o3 = fmaxf(o3, 0.f);
        }
        uint2 pw;
        pw.x = cvtpk(o0, o1);
        pw.y = cvtpk(o2, o3);
        *(uint2*)&T[row*128 + (col ^ ((row & 7) << 3))] = pw;
      }
    }
    __syncthreads();
    #pragma unroll
    for (int rr = 0; rr < 8; ++rr) {
      int row = rr*16 + (t >> 4);
      int cc  = t & 15;
      int sc  = cc ^ (row & 7);
      v8s vv = *(const v8s*)&T[row*128 + sc*8];
      if (QKV) {
        int m = bm + row;                           // j-major A rows
        int jj = m >> 8, i = m & 255;
        int n = bn + cc*8;
        int c = n & 255, proj = n >> 8;
        int hh = c >> 5, dd = c & 31;
        size_t idx = (size_t)proj*16777216 + (((size_t)hh*256 + jj)*256 + i)*32 + dd;
        *(v8s*)&((ushort*)Optr)[idx] = vv;
      } else {
        *(v8s*)&((ushort*)Optr)[(size_t)(bm + row)*ldo + bn + cc*8] = vv;
      }
    }
  } else {
    #pragma unroll
    for (int mi = 0; mi < 4; ++mi) {
      int m = bm + wm + mi*16 + lc;
      #pragma unroll
      for (int ni = 0; ni < 4; ++ni) {
        int n0 = bn + wn + ni*16 + lg*4;
        float4 bv = *(const float4*)&bias[n0];
        float o0 = acc[mi][ni][0] + bv.x;
        float o1 = acc[mi][ni][1] + bv.y;
        float o2 = acc[mi][ni][2] + bv.z;
        float o3 = acc[mi][ni][3] + bv.w;
        if (RELU) {
          o0 = fmaxf(o0, 0.f); o1 = fmaxf(o1, 0.f);
          o2 = fmaxf(o2, 0.f); o3 = fmaxf(o3, 0.f);
        }
        size_t idx = (size_t)m * ldo + n0;
        if (ADD) {
          float4 r4 = *(const float4*)&((const float*)Rp)[idx];
          o0 += r4.x; o1 += r4.y; o2 += r4.z; o3 += r4.w;
        }
        if (ADDB) {
          uint2 rb = *(const uint2*)&((const ushort*)Rp)[idx];
          o0 += bf2f((ushort)(rb.x & 0xFFFF));
          o1 += bf2f((ushort)(rb.x >> 16));
          o2 += bf2f((ushort)(rb.y & 0xFFFF));
          o3 += bf2f((ushort)(rb.y >> 16));
        }
        if (OUTBF16) {
          uint2 pr;
          pr.x = cvtpk(o0, o1);
          pr.y = cvtpk(o2, o3);
          *(uint2*)&((ushort*)Optr)[idx] = pr;
        } else {
          float4 so = {o0, o1, o2, o3};
          *(float4*)&((float*)Optr)[idx] = so;
        }
      }
    }
  }
}

// ---------------- fused Wo-GEMM + residual + LN2 (bf16 pr out, in-place) -----
__global__ __launch_bounds__(512) void wo_ln_k(
    const ushort* A, const ushort* __restrict__ W,
    const float* __restrict__ bo, const float* __restrict__ R,
    ushort* prb,
    const float* __restrict__ g2, const float* __restrict__ be2,
    ushort* __restrict__ yb) {
  __shared__ __align__(16) ushort As[128][64];   // 16KB
  __shared__ __align__(16) ushort Bs[256][64];   // 32KB
  int f = blockIdx.x;
  int sw = (f & 7) * (gridDim.x >> 3) + (f >> 3);   // grid=512, %8==0
  const int bm = sw * 128;
  const int t  = threadIdx.x;
  const int lane = t & 63, w = t >> 6;              // w 0..7
  const int wm = (w >> 2) * 64, wn = (w & 3) * 64;  // 2m x 4n waves
  const int lg = lane >> 4, lc = lane & 15;
  const int srow0 = t >> 3;          // 0..63
  const int scc   = t & 7;           // 16B chunk index

  v4f acc[4][4];
  #pragma unroll
  for (int i = 0; i < 4; ++i)
    #pragma unroll
    for (int jj = 0; jj < 4; ++jj) acc[i][jj] = (v4f){0.f,0.f,0.f,0.f};

  for (int k0 = 0; k0 < 256; k0 += 64) {
    #pragma unroll
    for (int s = 0; s < 2; ++s) {                   // A: 128 rows
      int row = s*64 + srow0;
      int gc  = (scc ^ (row & 7)) * 8;
      gload16(&A[(size_t)(bm + row)*256 + k0 + gc], (char*)As + s*8192 + t*16);
    }
    #pragma unroll
    for (int s = 0; s < 4; ++s) {                   // W: 256 rows (all of Wo)
      int row = s*64 + srow0;
      int gc  = (scc ^ (row & 7)) * 8;
      gload16(&W[(size_t)row*256 + k0 + gc], (char*)Bs + s*8192 + t*16);
    }
    __syncthreads();
    #pragma unroll
    for (int kh = 0; kh < 2; ++kh) {
      v8s af[4], bf_[4];
      #pragma unroll
      for (int mi = 0; mi < 4; ++mi) {
        int row = wm + mi*16 + lc;
        int cd  = ((kh*4 + lg) ^ (row & 7)) * 16;
        af[mi] = *(const v8s*)((const char*)As + row*128 + cd);
      }
      #pragma unroll
      for (int ni = 0; ni < 4; ++ni) {
        int row = wn + ni*16 + lc;
        int cd  = ((kh*4 + lg) ^ (row & 7)) * 16;
        bf_[ni] = *(const v8s*)((const char*)Bs + row*128 + cd);
      }
      #pragma unroll
      for (int mi = 0; mi < 4; ++mi)
        #pragma unroll
        for (int ni = 0; ni < 4; ++ni)
          acc[mi][ni] = __builtin_amdgcn_mfma_f32_16x16x32_bf16(bf_[ni], af[mi], acc[mi][ni], 0, 0, 0);
    }
    __syncthreads();   // after final iter: all LDS reads drained -> As reusable
  }

  // pr into acc (+ write bf16 prb in-place) + per-lane row partial sums
  float sum_mi[4], ssq_mi[4];
  #pragma unroll
  for (int mi = 0; mi < 4; ++mi) {
    int m = bm + wm + mi*16 + lc;
    float sm = 0.f, sq = 0.f;
    #pragma unroll
    for (int ni = 0; ni < 4; ++ni) {
      int n0 = wn + ni*16 + lg*4;
      float4 bv = *(const float4*)&bo[n0];
      float4 r4 = *(const float4*)&R[(size_t)m*256 + n0];
      float p0 = acc[mi][ni][0] + bv.x + r4.x;
      float p1 = acc[mi][ni][1] + bv.y + r4.y;
      float p2 = acc[mi][ni][2] + bv.z + r4.z;
      float p3 = acc[mi][ni][3] + bv.w + r4.w;
      acc[mi][ni][0] = p0; acc[mi][ni][1] = p1;
      acc[mi][ni][2] = p2; acc[mi][ni][3] = p3;
      uint2 pw;
      pw.x = cvtpk(p0, p1);
      pw.y = cvtpk(p2, p3);
      *(uint2*)&prb[(size_t)m*256 + n0] = pw;
      sm += (p0 + p1) + (p2 + p3);
      sq += (p0*p0 + p1*p1) + (p2*p2 + p3*p3);
    }
    sum_mi[mi] = sm; ssq_mi[mi] = sq;
  }
  // reduce over lg (xor 16, 32): per-wave 64-col partials
  #pragma unroll
  for (int mi = 0; mi < 4; ++mi) {
    sum_mi[mi] += __shfl_xor(sum_mi[mi], 16);
    sum_mi[mi] += __shfl_xor(sum_mi[mi], 32);
    ssq_mi[mi] += __shfl_xor(ssq_mi[mi], 16);
    ssq_mi[mi] += __shfl_xor(ssq_mi[mi], 32);
  }
  // cross-wave combine via LDS (reuse As: sum [0..512), sumsq [512..1024))
  float* sbuf = (float*)As;
  if (lg == 0) {
    #pragma unroll
    for (int mi = 0; mi < 4; ++mi) {
      int idx = w*64 + mi*16 + lc;
      sbuf[idx]       = sum_mi[mi];
      sbuf[512 + idx] = ssq_mi[mi];
    }
  }
  __syncthreads();
  #pragma unroll
  for (int mi = 0; mi < 4; ++mi) {
    int bi = (w >> 2)*256 + mi*16 + lc;   // (wm-half)*4 waves * 64
    float s = (sbuf[bi] + sbuf[bi+64]) + (sbuf[bi+128] + sbuf[bi+192]);
    float q = (sbuf[512+bi] + sbuf[512+bi+64]) + (sbuf[512+bi+128] + sbuf[512+bi+192]);
    float mu  = s * (1.0f/256.0f);
    float inv = rsqrtf(q * (1.0f/256.0f) - mu*mu + 1e-5f);
    int m = bm + wm + mi*16 + lc;
    #pragma unroll
    for (int ni = 0; ni < 4; ++ni) {
      int n0 = wn + ni*16 + lg*4;
      float4 gg = *(const float4*)&g2[n0];
      float4 bb = *(const float4*)&be2[n0];
      float y0 = (acc[mi][ni][0] - mu)*inv*gg.x + bb.x;
      float y1 = (acc[mi][ni][1] - mu)*inv*gg.y + bb.y;
      float y2 = (acc[mi][ni][2] - mu)*inv*gg.z + bb.z;
      float y3 = (acc[mi][ni][3] - mu)*inv*gg.w + bb.w;
      uint2 pr;
      pr.x = cvtpk(y0, y1);
      pr.y = cvtpk(y2, y3);
      *(uint2*)&yb[(size_t)m*256 + n0] = pr;
    }
  }
}

// ---------------- attention per (j,h): dual-qb interleaved chains ------------
// Both q-blocks of a wave processed in ONE chunk loop: K/V fragments are
// qb-independent and now loaded once; the two softmax/PV chains are
// independent -> 2x ILP for this latency-bound kernel.
// Fixed-shift softmax: p = exp2(s*scale + b*log2e - 8), no running max.
__global__ __launch_bounds__(256, 3) void attn9(
    const ushort* __restrict__ qt, const ushort* __restrict__ kt,
    const ushort* __restrict__ vt, const float* __restrict__ bM4,
    ushort* __restrict__ ao) {
  __shared__ __align__(16) ushort Vt[32][264];    // [d][key]
  const int j = blockIdx.x & 255, h = blockIdx.x >> 8;
  const int t = threadIdx.x, w = t >> 6, lane = t & 63;
  const int l5 = lane & 31, h5 = lane >> 5;
  const size_t base = ((size_t)(h*256 + j)) * 8192;

  {
    const ushort* vsrc = vt + base;
    int k4 = (t & 63) * 4, sd = (t >> 6) * 8;
    v8s v0 = *(const v8s*)&vsrc[(k4+0)*32 + sd];
    v8s v1 = *(const v8s*)&vsrc[(k4+1)*32 + sd];
    v8s v2 = *(const v8s*)&vsrc[(k4+2)*32 + sd];
    v8s v3 = *(const v8s*)&vsrc[(k4+3)*32 + sd];
    #pragma unroll
    for (int u = 0; u < 8; ++u) {
      ushort4 q4 = { (ushort)v0[u], (ushort)v1[u], (ushort)v2[u], (ushort)v3[u] };
      *(ushort4*)&Vt[sd+u][k4] = q4;
    }
  }
  __syncthreads();   // only barrier

  const ushort* ksrc = kt + base;
  const ushort* qsrc = qt + base;

  const int qbA = w*2, qbB = w*2 + 1;
  v8s qfA0 = *(const v8s*)&qsrc[(qbA*32 + l5)*32 + h5*8];
  v8s qfA1 = *(const v8s*)&qsrc[(qbA*32 + l5)*32 + 16 + h5*8];
  v8s qfB0 = *(const v8s*)&qsrc[(qbB*32 + l5)*32 + h5*8];
  v8s qfB1 = *(const v8s*)&qsrc[(qbB*32 + l5)*32 + 16 + h5*8];
  const float* bqbA = bM4 + (size_t)(h*8 + qbA) * 8192;
  const float* bqbB = bM4 + (size_t)(h*8 + qbB) * 8192;
  v16f oA = Z16, oB = Z16;
  float lA = 0.f, lB = 0.f;

  #pragma unroll 2
  for (int c = 0; c < 8; ++c) {
    // shared K fragments (qb-independent)
    v8s kf0 = *(const v8s*)&ksrc[(c*32 + l5)*32 + h5*8];
    v8s kf1 = *(const v8s*)&ksrc[(c*32 + l5)*32 + 16 + h5*8];
    v16f sA = __builtin_amdgcn_mfma_f32_32x32x16_bf16(kf0, qfA0, Z16, 0, 0, 0);
    sA = __builtin_amdgcn_mfma_f32_32x32x16_bf16(kf1, qfA1, sA, 0, 0, 0);
    v16f sB = __builtin_amdgcn_mfma_f32_32x32x16_bf16(kf0, qfB0, Z16, 0, 0, 0);
    sB = __builtin_amdgcn_mfma_f32_32x32x16_bf16(kf1, qfB1, sB, 0, 0, 0);
    // two independent softmax chains
    float pA[16], pB[16];
    #pragma unroll
    for (int r4 = 0; r4 < 4; ++r4) {
      float4 bA = *(const float4*)&bqbA[((c*2 + h5)*4 + r4)*128 + l5*4];
      float4 bB = *(const float4*)&bqbB[((c*2 + h5)*4 + r4)*128 + l5*4];
      pA[r4*4+0] = __builtin_amdgcn_exp2f(fmaf(sA[r4*4+0], SCALE2_, bA.x));
      pA[r4*4+1] = __builtin_amdgcn_exp2f(fmaf(sA[r4*4+1], SCALE2_, bA.y));
      pA[r4*4+2] = __builtin_amdgcn_exp2f(fmaf(sA[r4*4+2], SCALE2_, bA.z));
      pA[r4*4+3] = __builtin_amdgcn_exp2f(fmaf(sA[r4*4+3], SCALE2_, bA.w));
      pB[r4*4+0] = __builtin_amdgcn_exp2f(fmaf(sB[r4*4+0], SCALE2_, bB.x));
      pB[r4*4+1] = __builtin_amdgcn_exp2f(fmaf(sB[r4*4+1], SCALE2_, bB.y));
      pB[r4*4+2] = __builtin_amdgcn_exp2f(fmaf(sB[r4*4+2], SCALE2_, bB.z));
      pB[r4*4+3] = __builtin_amdgcn_exp2f(fmaf(sB[r4*4+3], SCALE2_, bB.w));
    }
    #pragma unroll
    for (int r = 0; r < 16; ++r) { lA += pA[r]; lB += pB[r]; }
    uint pkA[8], pkB[8];
    #pragma unroll
    for (int i2 = 0; i2 < 8; ++i2) {
      pkA[i2] = cvtpk(pA[2*i2], pA[2*i2+1]);
      pkB[i2] = cvtpk(pB[2*i2], pB[2*i2+1]);
    }
    uint a0 = pkA[0], a2 = pkA[2]; pl32swap(a0, a2);
    uint a1 = pkA[1], a3 = pkA[3]; pl32swap(a1, a3);
    uint a4 = pkA[4], a6 = pkA[6]; pl32swap(a4, a6);
    uint a5 = pkA[5], a7 = pkA[7]; pl32swap(a5, a7);
    uint b0 = pkB[0], b2 = pkB[2]; pl32swap(b0, b2);
    uint b1 = pkB[1], b3 = pkB[3]; pl32swap(b1, b3);
    uint b4 = pkB[4], b6 = pkB[6]; pl32swap(b4, b6);
    uint b5 = pkB[5], b7 = pkB[7]; pl32swap(b5, b7);
    uint4 BA1 = {a0, a1, a2, a3};
    uint4 BA2 = {a4, a5, a6, a7};
    uint4 BB1 = {b0, b1, b2, b3};
    uint4 BB2 = {b4, b5, b6, b7};
    // shared V fragments
    v8s vA1 = *(const v8s*)&Vt[l5][c*32 + h5*8];
    v8s vA2 = *(const v8s*)&Vt[l5][c*32 + 16 + h5*8];
    oA = __builtin_amdgcn_mfma_f32_32x32x16_bf16(vA1, *(v8s*)&BA1, oA, 0, 0, 0);
    oA = __builtin_amdgcn_mfma_f32_32x32x16_bf16(vA2, *(v8s*)&BA2, oA, 0, 0, 0);
    oB = __builtin_amdgcn_mfma_f32_32x32x16_bf16(vA1, *(v8s*)&BB1, oB, 0, 0, 0);
    oB = __builtin_amdgcn_mfma_f32_32x32x16_bf16(vA2, *(v8s*)&BB2, oB, 0, 0, 0);
  }
  // epilogue: both q-blocks
  {
    float lt = lA + __shfl_xor(lA, 32);
    float inv = 1.0f / lt;
    size_t ob = ((size_t)(qbA*32 + l5)*256 + j)*256 + h*32;
    #pragma unroll
    for (int r4 = 0; r4 < 4; ++r4) {
      uint2 pr;
      pr.x = cvtpk(oA[4*r4+0]*inv, oA[4*r4+1]*inv);
      pr.y = cvtpk(oA[4*r4+2]*inv, oA[4*r4+3]*inv);
      *(uint2*)&ao[ob + 8*r4 + 4*h5] = pr;
    }
  }
  {
    float lt = lB + __shfl_xor(lB, 32);
    float inv = 1.0f / lt;
    size_t ob = ((size_t)(qbB*32 + l5)*256 + j)*256 + h*32;
    #pragma unroll
    for (int r4 = 0; r4 < 4; ++r4) {
      uint2 pr;
      pr.x = cvtpk(oB[4*r4+0]*inv, oB[4*r4+1]*inv);
      pr.y = cvtpk(oB[4*r4+2]*inv, oB[4*r4+3]*inv);
      *(uint2*)&ao[ob + 8*r4 + 4*h5] = pr;
    }
  }
}

extern "C" void kernel_launch(void* const* d_in, const int* in_sizes, int n_in,
                              void* d_out, int out_size, void* d_ws, size_t ws_size,
                              hipStream_t stream) {
  const float* pair_repr = (const float*)d_in[0];
  const float* pair_bias = (const float*)d_in[1];
  const float* Wq = (const float*)d_in[2];
  const float* bq = (const float*)d_in[3];
  const float* Wk = (const float*)d_in[4];
  const float* bk = (const float*)d_in[5];
  const float* Wv = (const float*)d_in[6];
  const float* bv = (const float*)d_in[7];
  const float* Wo = (const float*)d_in[8];
  const float* bo = (const float*)d_in[9];
  const float* W1 = (const float*)d_in[10];
  const float* b1 = (const float*)d_in[11];
  const float* W2 = (const float*)d_in[12];
  const float* b2 = (const float*)d_in[13];
  const float* g1 = (const float*)d_in[14];
  const float* be1= (const float*)d_in[15];
  const float* g2 = (const float*)d_in[16];
  const float* be2= (const float*)d_in[17];
  const int* mask = (const int*)d_in[18];
  float* out = (float*)d_out;

  char* wsb = (char*)d_ws;
  ushort* xb = (ushort*)wsb;                    // region A: LN1 out -> ao -> prb
  ushort* ao = (ushort*)wsb;
  ushort* prb = (ushort*)wsb;                   // pr bf16, in-place over ao
  ushort* qt = (ushort*)(wsb + 33554432);       // region B: q_t -> yb
  ushort* yb = qt;
  ushort* kt = (ushort*)(wsb + 67108864);       // region C: k_t, v_t -> hb
  ushort* vt = (ushort*)(wsb + 100663296);
  ushort* hb = kt;
  char* d0 = wsb + 134217728;                   // region D: weights/bias
  ushort* Wqkvb = (ushort*)d0;
  ushort* Wob   = (ushort*)(d0 + 393216);
  ushort* W1b   = (ushort*)(d0 + 524288);
  ushort* W2b   = (ushort*)(d0 + 786432);
  float*  bqkv  = (float*)(d0 + 1048576);
  float*  bM4   = (float*)(d0 + 1052672);

  // 0. prep
  prep_k<<<dim3(1025), 256, 0, stream>>>(Wq, Wk, Wv, Wo, W1, W2, bq, bk, bv,
                                         pair_bias, mask, Wqkvb, Wob, W1b, W2b, bqkv, bM4);
  // 1. x = LN1(pair_repr) -> xb (j-major rows)
  ln_k<true><<<dim3(M_/4), 256, 0, stream>>>(pair_repr, g1, be1, xb);
  // 2. qkv projection -> head-major qt/kt/vt (LDS-transpose coalesced stores)
  gemm5<true,false,false,false,true><<<dim3(3072), 256, 0, stream>>>(
      xb, Wqkvb, bqkv, nullptr, (void*)qt, 768, C_, C_, 0, 6);
  // 3. attention -> ao (region A; xb dead)
  attn9<<<dim3(L_*H_), 256, 0, stream>>>(qt, kt, vt, bM4, ao);
  // 4+5. pr(bf16) = ao@Wo.T + bo + pair_repr -> prb (in-place); y = LN2 -> yb
  wo_ln_k<<<dim3(512), 512, 0, stream>>>(ao, Wob, bo, pair_repr, prb, g2, be2, yb);
  // 6. h = relu(y@W1.T + b1) -> hb (LDS-transpose coalesced stores)
  gemm5<true,true,false,false,false><<<dim3(2048), 256, 0, stream>>>(
      yb, W1b, b1, nullptr, (void*)hb, F_, C_, C_, F_, 4);
  // 7. out = prb + h@W2.T + b2 -> d_out (fp32, sole writer of out)
  gemm5<false,false,false,true,false><<<dim3(1024), 256, 0, stream>>>(
      hb, W2b, b2, prb, out, C_, F_, F_, C_, 2);
}

// Round 20
// 225.251 us; speedup vs baseline: 1.0313x; 1.0313x over previous
//
#include <hip/hip_runtime.h>

#define L_ 256
#define C_ 256
#define H_ 8
#define D_ 32
#define F_ 512
#define M_ (L_*L_)   // 65536 rows
#define SCALE2_ 0.2550348564624926f   // (1/sqrt(32)) * log2(e)
#define LOG2E_  1.4426950408889634f

typedef __attribute__((ext_vector_type(8))) short v8s;    // 8 bf16 = 16B
typedef __attribute__((ext_vector_type(4))) float v4f;    // 16x16 MFMA acc
typedef __attribute__((ext_vector_type(16))) float v16f;  // 32x32 MFMA acc
#define Z16 (v16f){0,0,0,0,0,0,0,0,0,0,0,0,0,0,0,0}

__device__ __forceinline__ ushort f2bf(float f) {
  union { float f; unsigned u; } v; v.f = f;
  unsigned r = v.u + 0x7FFFu + ((v.u >> 16) & 1u);   // RNE
  return (ushort)(r >> 16);
}

__device__ __forceinline__ float bf2f(ushort u) {
  union { unsigned u; float f; } v; v.u = (unsigned)u << 16;
  return v.f;
}

// pack 2 fp32 -> 2 bf16 in one instr (RNE); lo -> bits 0-15
__device__ __forceinline__ uint cvtpk(float lo, float hi) {
  uint r;
  asm("v_cvt_pk_bf16_f32 %0, %1, %2" : "=v"(r) : "v"(lo), "v"(hi));
  return r;
}

__device__ __forceinline__ void gload16(const void* g, void* l) {
  __builtin_amdgcn_global_load_lds(
      (const __attribute__((address_space(1))) void*)g,
      (__attribute__((address_space(3))) void*)l, 16, 0, 0);
}

// half-exchange: a' = [a.lo | b.lo], b' = [a.hi | b.hi]
__device__ __forceinline__ void pl32swap(uint &a, uint &b) {
  asm volatile("v_permlane32_swap_b32 %0, %1" : "+v"(a), "+v"(b));
}

// ---------------- prep: weights -> bf16, bias retile for 32x32 path ----------
// bM4 entries carry the fixed softmax shift: b*log2e - 8 (softmax is
// shift-invariant; bf16/fp32 share exponent range so no stability cost).
__global__ __launch_bounds__(256) void prep_k(
    const float* __restrict__ Wq, const float* __restrict__ Wk,
    const float* __restrict__ Wv, const float* __restrict__ Wo,
    const float* __restrict__ W1, const float* __restrict__ W2,
    const float* __restrict__ bq, const float* __restrict__ bk,
    const float* __restrict__ bv,
    const float* __restrict__ bias, const int* __restrict__ mask,
    ushort* __restrict__ Wqkvb, ushort* __restrict__ Wob,
    ushort* __restrict__ W1b, ushort* __restrict__ W2b,
    float* __restrict__ bqkv, float* __restrict__ bM4) {
  int idx = blockIdx.x * 256 + threadIdx.x;
  if (idx < 49152) {                             // Wqkv: 768x256
    int e = idx * 4; int n = e >> 8; int k = e & 255;
    const float* src = n < 256 ? &Wq[n*256 + k]
                     : n < 512 ? &Wk[(n-256)*256 + k]
                               : &Wv[(n-512)*256 + k];
    float4 f = *(const float4*)src;
    ushort4 o = { f2bf(f.x), f2bf(f.y), f2bf(f.z), f2bf(f.w) };
    *(ushort4*)&Wqkvb[e] = o;
  } else if (idx < 65536) {                      // Wo: 256x256
    int e = (idx - 49152) * 4;
    float4 f = *(const float4*)&Wo[e];
    ushort4 o = { f2bf(f.x), f2bf(f.y), f2bf(f.z), f2bf(f.w) };
    *(ushort4*)&Wob[e] = o;
  } else if (idx < 98304) {                      // W1: 512x256
    int e = (idx - 65536) * 4;
    float4 f = *(const float4*)&W1[e];
    ushort4 o = { f2bf(f.x), f2bf(f.y), f2bf(f.z), f2bf(f.w) };
    *(ushort4*)&W1b[e] = o;
  } else if (idx < 131072) {                     // W2: 256x512
    int e = (idx - 98304) * 4;
    float4 f = *(const float4*)&W2[e];
    ushort4 o = { f2bf(f.x), f2bf(f.y), f2bf(f.z), f2bf(f.w) };
    *(ushort4*)&W2b[e] = o;
  } else if (idx < 262144) {                     // bM4[h][qb][c][h5][r4][q32][j]
    int eb = idx - 131072;
    int q32 = eb & 31, r4 = (eb >> 5) & 3, h5 = (eb >> 7) & 1;
    int c = (eb >> 8) & 7, qb = (eb >> 11) & 7, h = eb >> 14;
    int q = qb*32 + q32;
    int keyb = 32*c + 8*r4 + 4*h5;
    float4 b4 = *(const float4*)&bias[((size_t)(h*256 + q))*256 + keyb];
    int4   m4 = *(const int4*)&mask[(size_t)q*256 + keyb];
    float4 o;
    o.x = m4.x ? b4.x * LOG2E_ - 8.0f : -1e30f;
    o.y = m4.y ? b4.y * LOG2E_ - 8.0f : -1e30f;
    o.z = m4.z ? b4.z * LOG2E_ - 8.0f : -1e30f;
    o.w = m4.w ? b4.w * LOG2E_ - 8.0f : -1e30f;
    *(float4*)&bM4[(size_t)eb*4] = o;
  } else if (idx < 262336) {                     // bqkv: 768
    int e = (idx - 262144) * 4;
    const float* src = e < 256 ? &bq[e] : e < 512 ? &bk[e-256] : &bv[e-512];
    *(float4*)&bqkv[e] = *(const float4*)src;
  }
}

// ---------------- LayerNorm; TR=true writes j-major rows ---------------------
template<bool TR>
__global__ __launch_bounds__(256) void ln_k(const float* __restrict__ in,
    const float* __restrict__ g, const float* __restrict__ b,
    ushort* __restrict__ out) {
  int wid = threadIdx.x >> 6, lane = threadIdx.x & 63;
  size_t row = (size_t)blockIdx.x * 4 + wid;
  const float* x = in + row * C_;
  float4 v = *(const float4*)&x[lane*4];
  float s  = v.x + v.y + v.z + v.w;
  float s2 = v.x*v.x + v.y*v.y + v.z*v.z + v.w*v.w;
  #pragma unroll
  for (int off = 1; off < 64; off <<= 1) {
    s  += __shfl_xor(s,  off);
    s2 += __shfl_xor(s2, off);
  }
  float mean = s * (1.0f/C_);
  float var  = s2 * (1.0f/C_) - mean*mean;
  float inv  = rsqrtf(var + 1e-5f);
  float4 gg = *(const float4*)&g[lane*4];
  float4 bb = *(const float4*)&b[lane*4];
  ushort4 o;
  o.x = f2bf((v.x-mean)*inv*gg.x + bb.x);
  o.y = f2bf((v.y-mean)*inv*gg.y + bb.y);
  o.z = f2bf((v.z-mean)*inv*gg.z + bb.z);
  o.w = f2bf((v.w-mean)*inv*gg.w + bb.w);
  size_t orow = TR ? ((row & 255) * 256 + (row >> 8)) : row;
  *(ushort4*)&out[orow*C_ + lane*4] = o;
}

// ---------------- bf16 MFMA NT GEMM: BK=64, swizzled LDS ---------------------
// bf16 outputs (QKV / plain OUTBF16) go through an LDS-transpose epilogue so
// each lane stores 16B and waves emit full-cache-line runs.
// ADD: fp32 residual; ADDB: bf16 residual. R/Optr NOT restrict-qualified.
template<bool OUTBF16, bool RELU, bool ADD, bool ADDB, bool QKV>
__global__ __launch_bounds__(256) void gemm5(
    const ushort* __restrict__ A, const ushort* __restrict__ W,
    const float* __restrict__ bias, const void* Rp,
    void* Optr, int N, int K, int lda, int ldo, int nby) {
  __shared__ __align__(16) ushort LDSb[2][128][64];   // As=LDSb[0], Bs=LDSb[1]
  constexpr bool LDST = QKV || (OUTBF16 && !ADD && !ADDB);
  int f = blockIdx.x;
  int sw = (f & 7) * (gridDim.x >> 3) + (f >> 3);   // XCD-bijective (grid%8==0)
  const int bm = (sw / nby) * 128;
  const int bn = (sw % nby) * 128;
  const int t  = threadIdx.x;
  const int lane = t & 63, w = t >> 6;
  const int wm = (w >> 1) * 64, wn = (w & 1) * 64;
  const int lg = lane >> 4, lc = lane & 15;
  const int srow0 = t >> 3;          // 0..31
  const int scc   = t & 7;           // 16B chunk index

  v4f acc[4][4];
  #pragma unroll
  for (int i = 0; i < 4; ++i)
    #pragma unroll
    for (int jj = 0; jj < 4; ++jj) acc[i][jj] = (v4f){0.f,0.f,0.f,0.f};

  for (int k0 = 0; k0 < K; k0 += 64) {
    // stage: LDS[row][cc] <- global chunk (cc ^ (row&7))  [involution]
    #pragma unroll
    for (int s = 0; s < 4; ++s) {
      int row = s*32 + srow0;
      int gc  = (scc ^ (row & 7)) * 8;
      gload16(&A[(size_t)(bm + row)*lda + k0 + gc], (char*)LDSb + s*4096 + t*16);
      gload16(&W[(size_t)(bn + row)*K  + k0 + gc], (char*)LDSb + 16384 + s*4096 + t*16);
    }
    __syncthreads();
    #pragma unroll
    for (int kh = 0; kh < 2; ++kh) {
      v8s af[4], bf_[4];
      #pragma unroll
      for (int mi = 0; mi < 4; ++mi) {
        int row = wm + mi*16 + lc;
        int cd  = ((kh*4 + lg) ^ (row & 7)) * 16;
        af[mi] = *(const v8s*)((const char*)LDSb + row*128 + cd);
      }
      #pragma unroll
      for (int ni = 0; ni < 4; ++ni) {
        int row = wn + ni*16 + lc;
        int cd  = ((kh*4 + lg) ^ (row & 7)) * 16;
        bf_[ni] = *(const v8s*)((const char*)LDSb + 16384 + row*128 + cd);
      }
      // swapped operands: D row-index <- W (n), col-index <- A (m)
      #pragma unroll
      for (int mi = 0; mi < 4; ++mi)
        #pragma unroll
        for (int ni = 0; ni < 4; ++ni)
          acc[mi][ni] = __builtin_amdgcn_mfma_f32_16x16x32_bf16(bf_[ni], af[mi], acc[mi][ni], 0, 0, 0);
    }
    __syncthreads();
  }
  // epilogue: lane owns O[m = bm+wm+mi*16+lc][n0 .. n0+3], n0 = bn+wn+ni*16+lg*4
  if (LDST) {
    // stage bf16 tile in LDS (XOR-swizzled), then 16B/lane coalesced stores
    ushort* T = (ushort*)LDSb;   // [128][128]
    #pragma unroll
    for (int mi = 0; mi < 4; ++mi) {
      int row = wm + mi*16 + lc;
      #pragma unroll
      for (int ni = 0; ni < 4; ++ni) {
        int col = wn + ni*16 + lg*4;
        float4 bv = *(const float4*)&bias[bn + col];
        float o0 = acc[mi][ni][0] + bv.x;
        float o1 = acc[mi][ni][1] + bv.y;
        float o2 = acc[mi][ni][2] + bv.z;
        float o3 = acc[mi][ni][3] + bv.w;
        if (RELU) {
          o0 = fmaxf(o0, 0.f); o1 = fmaxf(o1, 0.f);
          o2 = fmaxf(o2, 0.f); o3 = fmaxf(o3, 0.f);
        }
        uint2 pw;
        pw.x = cvtpk(o0, o1);
        pw.y = cvtpk(o2, o3);
        *(uint2*)&T[row*128 + (col ^ ((row & 7) << 3))] = pw;
      }
    }
    __syncthreads();
    #pragma unroll
    for (int rr = 0; rr < 8; ++rr) {
      int row = rr*16 + (t >> 4);
      int cc  = t & 15;
      int sc  = cc ^ (row & 7);
      v8s vv = *(const v8s*)&T[row*128 + sc*8];
      if (QKV) {
        int m = bm + row;                           // j-major A rows
        int jj = m >> 8, i = m & 255;
        int n = bn + cc*8;
        int c = n & 255, proj = n >> 8;
        int hh = c >> 5, dd = c & 31;
        size_t idx = (size_t)proj*16777216 + (((size_t)hh*256 + jj)*256 + i)*32 + dd;
        *(v8s*)&((ushort*)Optr)[idx] = vv;
      } else {
        *(v8s*)&((ushort*)Optr)[(size_t)(bm + row)*ldo + bn + cc*8] = vv;
      }
    }
  } else {
    #pragma unroll
    for (int mi = 0; mi < 4; ++mi) {
      int m = bm + wm + mi*16 + lc;
      #pragma unroll
      for (int ni = 0; ni < 4; ++ni) {
        int n0 = bn + wn + ni*16 + lg*4;
        float4 bv = *(const float4*)&bias[n0];
        float o0 = acc[mi][ni][0] + bv.x;
        float o1 = acc[mi][ni][1] + bv.y;
        float o2 = acc[mi][ni][2] + bv.z;
        float o3 = acc[mi][ni][3] + bv.w;
        if (RELU) {
          o0 = fmaxf(o0, 0.f); o1 = fmaxf(o1, 0.f);
          o2 = fmaxf(o2, 0.f); o3 = fmaxf(o3, 0.f);
        }
        size_t idx = (size_t)m * ldo + n0;
        if (ADD) {
          float4 r4 = *(const float4*)&((const float*)Rp)[idx];
          o0 += r4.x; o1 += r4.y; o2 += r4.z; o3 += r4.w;
        }
        if (ADDB) {
          uint2 rb = *(const uint2*)&((const ushort*)Rp)[idx];
          o0 += bf2f((ushort)(rb.x & 0xFFFF));
          o1 += bf2f((ushort)(rb.x >> 16));
          o2 += bf2f((ushort)(rb.y & 0xFFFF));
          o3 += bf2f((ushort)(rb.y >> 16));
        }
        if (OUTBF16) {
          uint2 pr;
          pr.x = cvtpk(o0, o1);
          pr.y = cvtpk(o2, o3);
          *(uint2*)&((ushort*)Optr)[idx] = pr;
        } else {
          float4 so = {o0, o1, o2, o3};
          *(float4*)&((float*)Optr)[idx] = so;
        }
      }
    }
  }
}

// ---------------- fused Wo-GEMM + residual + LN2 (bf16 pr out, in-place) -----
__global__ __launch_bounds__(512) void wo_ln_k(
    const ushort* A, const ushort* __restrict__ W,
    const float* __restrict__ bo, const float* __restrict__ R,
    ushort* prb,
    const float* __restrict__ g2, const float* __restrict__ be2,
    ushort* __restrict__ yb) {
  __shared__ __align__(16) ushort As[128][64];   // 16KB
  __shared__ __align__(16) ushort Bs[256][64];   // 32KB
  int f = blockIdx.x;
  int sw = (f & 7) * (gridDim.x >> 3) + (f >> 3);   // grid=512, %8==0
  const int bm = sw * 128;
  const int t  = threadIdx.x;
  const int lane = t & 63, w = t >> 6;              // w 0..7
  const int wm = (w >> 2) * 64, wn = (w & 3) * 64;  // 2m x 4n waves
  const int lg = lane >> 4, lc = lane & 15;
  const int srow0 = t >> 3;          // 0..63
  const int scc   = t & 7;           // 16B chunk index

  v4f acc[4][4];
  #pragma unroll
  for (int i = 0; i < 4; ++i)
    #pragma unroll
    for (int jj = 0; jj < 4; ++jj) acc[i][jj] = (v4f){0.f,0.f,0.f,0.f};

  for (int k0 = 0; k0 < 256; k0 += 64) {
    #pragma unroll
    for (int s = 0; s < 2; ++s) {                   // A: 128 rows
      int row = s*64 + srow0;
      int gc  = (scc ^ (row & 7)) * 8;
      gload16(&A[(size_t)(bm + row)*256 + k0 + gc], (char*)As + s*8192 + t*16);
    }
    #pragma unroll
    for (int s = 0; s < 4; ++s) {                   // W: 256 rows (all of Wo)
      int row = s*64 + srow0;
      int gc  = (scc ^ (row & 7)) * 8;
      gload16(&W[(size_t)row*256 + k0 + gc], (char*)Bs + s*8192 + t*16);
    }
    __syncthreads();
    #pragma unroll
    for (int kh = 0; kh < 2; ++kh) {
      v8s af[4], bf_[4];
      #pragma unroll
      for (int mi = 0; mi < 4; ++mi) {
        int row = wm + mi*16 + lc;
        int cd  = ((kh*4 + lg) ^ (row & 7)) * 16;
        af[mi] = *(const v8s*)((const char*)As + row*128 + cd);
      }
      #pragma unroll
      for (int ni = 0; ni < 4; ++ni) {
        int row = wn + ni*16 + lc;
        int cd  = ((kh*4 + lg) ^ (row & 7)) * 16;
        bf_[ni] = *(const v8s*)((const char*)Bs + row*128 + cd);
      }
      #pragma unroll
      for (int mi = 0; mi < 4; ++mi)
        #pragma unroll
        for (int ni = 0; ni < 4; ++ni)
          acc[mi][ni] = __builtin_amdgcn_mfma_f32_16x16x32_bf16(bf_[ni], af[mi], acc[mi][ni], 0, 0, 0);
    }
    __syncthreads();   // after final iter: all LDS reads drained -> As reusable
  }

  // pr into acc (+ write bf16 prb in-place) + per-lane row partial sums
  float sum_mi[4], ssq_mi[4];
  #pragma unroll
  for (int mi = 0; mi < 4; ++mi) {
    int m = bm + wm + mi*16 + lc;
    float sm = 0.f, sq = 0.f;
    #pragma unroll
    for (int ni = 0; ni < 4; ++ni) {
      int n0 = wn + ni*16 + lg*4;
      float4 bv = *(const float4*)&bo[n0];
      float4 r4 = *(const float4*)&R[(size_t)m*256 + n0];
      float p0 = acc[mi][ni][0] + bv.x + r4.x;
      float p1 = acc[mi][ni][1] + bv.y + r4.y;
      float p2 = acc[mi][ni][2] + bv.z + r4.z;
      float p3 = acc[mi][ni][3] + bv.w + r4.w;
      acc[mi][ni][0] = p0; acc[mi][ni][1] = p1;
      acc[mi][ni][2] = p2; acc[mi][ni][3] = p3;
      uint2 pw;
      pw.x = cvtpk(p0, p1);
      pw.y = cvtpk(p2, p3);
      *(uint2*)&prb[(size_t)m*256 + n0] = pw;
      sm += (p0 + p1) + (p2 + p3);
      sq += (p0*p0 + p1*p1) + (p2*p2 + p3*p3);
    }
    sum_mi[mi] = sm; ssq_mi[mi] = sq;
  }
  // reduce over lg (xor 16, 32): per-wave 64-col partials
  #pragma unroll
  for (int mi = 0; mi < 4; ++mi) {
    sum_mi[mi] += __shfl_xor(sum_mi[mi], 16);
    sum_mi[mi] += __shfl_xor(sum_mi[mi], 32);
    ssq_mi[mi] += __shfl_xor(ssq_mi[mi], 16);
    ssq_mi[mi] += __shfl_xor(ssq_mi[mi], 32);
  }
  // cross-wave combine via LDS (reuse As: sum [0..512), sumsq [512..1024))
  float* sbuf = (float*)As;
  if (lg == 0) {
    #pragma unroll
    for (int mi = 0; mi < 4; ++mi) {
      int idx = w*64 + mi*16 + lc;
      sbuf[idx]       = sum_mi[mi];
      sbuf[512 + idx] = ssq_mi[mi];
    }
  }
  __syncthreads();
  #pragma unroll
  for (int mi = 0; mi < 4; ++mi) {
    int bi = (w >> 2)*256 + mi*16 + lc;   // (wm-half)*4 waves * 64
    float s = (sbuf[bi] + sbuf[bi+64]) + (sbuf[bi+128] + sbuf[bi+192]);
    float q = (sbuf[512+bi] + sbuf[512+bi+64]) + (sbuf[512+bi+128] + sbuf[512+bi+192]);
    float mu  = s * (1.0f/256.0f);
    float inv = rsqrtf(q * (1.0f/256.0f) - mu*mu + 1e-5f);
    int m = bm + wm + mi*16 + lc;
    #pragma unroll
    for (int ni = 0; ni < 4; ++ni) {
      int n0 = wn + ni*16 + lg*4;
      float4 gg = *(const float4*)&g2[n0];
      float4 bb = *(const float4*)&be2[n0];
      float y0 = (acc[mi][ni][0] - mu)*inv*gg.x + bb.x;
      float y1 = (acc[mi][ni][1] - mu)*inv*gg.y + bb.y;
      float y2 = (acc[mi][ni][2] - mu)*inv*gg.z + bb.z;
      float y3 = (acc[mi][ni][3] - mu)*inv*gg.w + bb.w;
      uint2 pr;
      pr.x = cvtpk(y0, y1);
      pr.y = cvtpk(y2, y3);
      *(uint2*)&yb[(size_t)m*256 + n0] = pr;
    }
  }
}

// ---------------- attention per (j,h): fixed-shift softmax + T5 setprio ------
// r18-exact attn8 structure; MFMA clusters wrapped in s_setprio(1)/(0) —
// waves here run independent phases after the single barrier, the regime
// where setprio pays (guide m191: +4-7% attn; null on lockstep GEMM).
__global__ __launch_bounds__(256, 4) void attn8(
    const ushort* __restrict__ qt, const ushort* __restrict__ kt,
    const ushort* __restrict__ vt, const float* __restrict__ bM4,
    ushort* __restrict__ ao) {
  __shared__ __align__(16) ushort Vt[32][264];    // [d][key]
  const int j = blockIdx.x & 255, h = blockIdx.x >> 8;
  const int t = threadIdx.x, w = t >> 6, lane = t & 63;
  const int l5 = lane & 31, h5 = lane >> 5;
  const size_t base = ((size_t)(h*256 + j)) * 8192;

  {
    const ushort* vsrc = vt + base;
    int k4 = (t & 63) * 4, sd = (t >> 6) * 8;
    v8s v0 = *(const v8s*)&vsrc[(k4+0)*32 + sd];
    v8s v1 = *(const v8s*)&vsrc[(k4+1)*32 + sd];
    v8s v2 = *(const v8s*)&vsrc[(k4+2)*32 + sd];
    v8s v3 = *(const v8s*)&vsrc[(k4+3)*32 + sd];
    #pragma unroll
    for (int u = 0; u < 8; ++u) {
      ushort4 q4 = { (ushort)v0[u], (ushort)v1[u], (ushort)v2[u], (ushort)v3[u] };
      *(ushort4*)&Vt[sd+u][k4] = q4;
    }
  }
  __syncthreads();   // only barrier

  const ushort* ksrc = kt + base;
  const ushort* qsrc = qt + base;

  #pragma unroll 1
  for (int qi = 0; qi < 2; ++qi) {
    const int qb = w*2 + qi;
    v8s qf0 = *(const v8s*)&qsrc[(qb*32 + l5)*32 + h5*8];
    v8s qf1 = *(const v8s*)&qsrc[(qb*32 + l5)*32 + 16 + h5*8];
    const float* bqb = bM4 + (size_t)(h*8 + qb) * 8192;
    v16f o = Z16;
    float l = 0.f;

    #pragma unroll 2
    for (int c = 0; c < 8; ++c) {
      v8s kf0 = *(const v8s*)&ksrc[(c*32 + l5)*32 + h5*8];
      v8s kf1 = *(const v8s*)&ksrc[(c*32 + l5)*32 + 16 + h5*8];
      __builtin_amdgcn_s_setprio(1);
      v16f s = __builtin_amdgcn_mfma_f32_32x32x16_bf16(kf0, qf0, Z16, 0, 0, 0);
      s = __builtin_amdgcn_mfma_f32_32x32x16_bf16(kf1, qf1, s, 0, 0, 0);
      __builtin_amdgcn_s_setprio(0);
      // p = exp2(s*scale + shifted bias); accumulate l; pack pairs via cvt_pk
      float p[16];
      #pragma unroll
      for (int r4 = 0; r4 < 4; ++r4) {
        float4 b4 = *(const float4*)&bqb[((c*2 + h5)*4 + r4)*128 + l5*4];
        p[r4*4+0] = __builtin_amdgcn_exp2f(fmaf(s[r4*4+0], SCALE2_, b4.x));
        p[r4*4+1] = __builtin_amdgcn_exp2f(fmaf(s[r4*4+1], SCALE2_, b4.y));
        p[r4*4+2] = __builtin_amdgcn_exp2f(fmaf(s[r4*4+2], SCALE2_, b4.z));
        p[r4*4+3] = __builtin_amdgcn_exp2f(fmaf(s[r4*4+3], SCALE2_, b4.w));
      }
      #pragma unroll
      for (int r = 0; r < 16; ++r) l += p[r];
      uint pk[8];
      #pragma unroll
      for (int i2 = 0; i2 < 8; ++i2)
        pk[i2] = cvtpk(p[2*i2], p[2*i2+1]);
      uint w0 = pk[0], w2 = pk[2]; pl32swap(w0, w2);
      uint w1 = pk[1], w3 = pk[3]; pl32swap(w1, w3);
      uint w4 = pk[4], w6 = pk[6]; pl32swap(w4, w6);
      uint w5 = pk[5], w7 = pk[7]; pl32swap(w5, w7);
      uint4 B1 = {w0, w1, w2, w3};
      uint4 B2 = {w4, w5, w6, w7};
      v8s vA1 = *(const v8s*)&Vt[l5][c*32 + h5*8];
      v8s vA2 = *(const v8s*)&Vt[16 + l5 - (l5 & 16)*0][0];  // placeholder removed below
      (void)vA2;
      v8s vB1 = *(const v8s*)&Vt[l5][c*32 + h5*8];
      (void)vB1;
      v8s vv1 = *(const v8s*)&Vt[l5][c*32 + h5*8];
      v8s vv2 = *(const v8s*)&Vt[l5][c*32 + 16 + h5*8];
      __builtin_amdgcn_s_setprio(1);
      o = __builtin_amdgcn_mfma_f32_32x32x16_bf16(vv1, *(v8s*)&B1, o, 0, 0, 0);
      o = __builtin_amdgcn_mfma_f32_32x32x16_bf16(vv2, *(v8s*)&B2, o, 0, 0, 0);
      __builtin_amdgcn_s_setprio(0);
      (void)vA1;
    }
    float lt = l + __shfl_xor(l, 32);
    float inv = 1.0f / lt;
    size_t ob = ((size_t)(qb*32 + l5)*256 + j)*256 + h*32;
    #pragma unroll
    for (int r4 = 0; r4 < 4; ++r4) {
      uint2 pr;
      pr.x = cvtpk(o[4*r4+0]*inv, o[4*r4+1]*inv);
      pr.y = cvtpk(o[4*r4+2]*inv, o[4*r4+3]*inv);
      *(uint2*)&ao[ob + 8*r4 + 4*h5] = pr;
    }
  }
}

extern "C" void kernel_launch(void* const* d_in, const int* in_sizes, int n_in,
                              void* d_out, int out_size, void* d_ws, size_t ws_size,
                              hipStream_t stream) {
  const float* pair_repr = (const float*)d_in[0];
  const float* pair_bias = (const float*)d_in[1];
  const float* Wq = (const float*)d_in[2];
  const float* bq = (const float*)d_in[3];
  const float* Wk = (const float*)d_in[4];
  const float* bk = (const float*)d_in[5];
  const float* Wv = (const float*)d_in[6];
  const float* bv = (const float*)d_in[7];
  const float* Wo = (const float*)d_in[8];
  const float* bo = (const float*)d_in[9];
  const float* W1 = (const float*)d_in[10];
  const float* b1 = (const float*)d_in[11];
  const float* W2 = (const float*)d_in[12];
  const float* b2 = (const float*)d_in[13];
  const float* g1 = (const float*)d_in[14];
  const float* be1= (const float*)d_in[15];
  const float* g2 = (const float*)d_in[16];
  const float* be2= (const float*)d_in[17];
  const int* mask = (const int*)d_in[18];
  float* out = (float*)d_out;

  char* wsb = (char*)d_ws;
  ushort* xb = (ushort*)wsb;                    // region A: LN1 out -> ao -> prb
  ushort* ao = (ushort*)wsb;
  ushort* prb = (ushort*)wsb;                   // pr bf16, in-place over ao
  ushort* qt = (ushort*)(wsb + 33554432);       // region B: q_t -> yb
  ushort* yb = qt;
  ushort* kt = (ushort*)(wsb + 67108864);       // region C: k_t, v_t -> hb
  ushort* vt = (ushort*)(wsb + 100663296);
  ushort* hb = kt;
  char* d0 = wsb + 134217728;                   // region D: weights/bias
  ushort* Wqkvb = (ushort*)d0;
  ushort* Wob   = (ushort*)(d0 + 393216);
  ushort* W1b   = (ushort*)(d0 + 524288);
  ushort* W2b   = (ushort*)(d0 + 786432);
  float*  bqkv  = (float*)(d0 + 1048576);
  float*  bM4   = (float*)(d0 + 1052672);

  // 0. prep
  prep_k<<<dim3(1025), 256, 0, stream>>>(Wq, Wk, Wv, Wo, W1, W2, bq, bk, bv,
                                         pair_bias, mask, Wqkvb, Wob, W1b, W2b, bqkv, bM4);
  // 1. x = LN1(pair_repr) -> xb (j-major rows)
  ln_k<true><<<dim3(M_/4), 256, 0, stream>>>(pair_repr, g1, be1, xb);
  // 2. qkv projection -> head-major qt/kt/vt (LDS-transpose coalesced stores)
  gemm5<true,false,false,false,true><<<dim3(3072), 256, 0, stream>>>(
      xb, Wqkvb, bqkv, nullptr, (void*)qt, 768, C_, C_, 0, 6);
  // 3. attention -> ao (region A; xb dead)
  attn8<<<dim3(L_*H_), 256, 0, stream>>>(qt, kt, vt, bM4, ao);
  // 4+5. pr(bf16) = ao@Wo.T + bo + pair_repr -> prb (in-place); y = LN2 -> yb
  wo_ln_k<<<dim3(512), 512, 0, stream>>>(ao, Wob, bo, pair_repr, prb, g2, be2, yb);
  // 6. h = relu(y@W1.T + b1) -> hb (LDS-transpose coalesced stores)
  gemm5<true,true,false,false,false><<<dim3(2048), 256, 0, stream>>>(
      yb, W1b, b1, nullptr, (void*)hb, F_, C_, C_, F_, 4);
  // 7. out = prb + h@W2.T + b2 -> d_out (fp32, sole writer of out)
  gemm5<false,false,false,true,false><<<dim3(1024), 256, 0, stream>>>(
      hb, W2b, b2, prb, out, C_, F_, F_, C_, 2);
}

// Round 21
// 214.127 us; speedup vs baseline: 1.0849x; 1.0520x over previous
//
#include <hip/hip_runtime.h>

#define L_ 256
#define C_ 256
#define H_ 8
#define D_ 32
#define F_ 512
#define M_ (L_*L_)   // 65536 rows
#define SCALE2_ 0.2550348564624926f   // (1/sqrt(32)) * log2(e)
#define LOG2E_  1.4426950408889634f

typedef __attribute__((ext_vector_type(8))) short v8s;    // 8 bf16 = 16B
typedef __attribute__((ext_vector_type(4))) float v4f;    // 16x16 MFMA acc
typedef __attribute__((ext_vector_type(16))) float v16f;  // 32x32 MFMA acc
#define Z16 (v16f){0,0,0,0,0,0,0,0,0,0,0,0,0,0,0,0}

__device__ __forceinline__ ushort f2bf(float f) {
  union { float f; unsigned u; } v; v.f = f;
  unsigned r = v.u + 0x7FFFu + ((v.u >> 16) & 1u);   // RNE
  return (ushort)(r >> 16);
}

__device__ __forceinline__ float bf2f(ushort u) {
  union { unsigned u; float f; } v; v.u = (unsigned)u << 16;
  return v.f;
}

// pack 2 fp32 -> 2 bf16 in one instr (RNE); lo -> bits 0-15
__device__ __forceinline__ uint cvtpk(float lo, float hi) {
  uint r;
  asm("v_cvt_pk_bf16_f32 %0, %1, %2" : "=v"(r) : "v"(lo), "v"(hi));
  return r;
}

__device__ __forceinline__ void gload16(const void* g, void* l) {
  __builtin_amdgcn_global_load_lds(
      (const __attribute__((address_space(1))) void*)g,
      (__attribute__((address_space(3))) void*)l, 16, 0, 0);
}

// half-exchange: a' = [a.lo | b.lo], b' = [a.hi | b.hi]
__device__ __forceinline__ void pl32swap(uint &a, uint &b) {
  asm volatile("v_permlane32_swap_b32 %0, %1" : "+v"(a), "+v"(b));
}

// ---------------- prep: weights -> bf16, bias retile for 32x32 path ----------
// bM4 entries carry the fixed softmax shift: b*log2e - 8 (softmax is
// shift-invariant; bf16/fp32 share exponent range so no stability cost).
__global__ __launch_bounds__(256) void prep_k(
    const float* __restrict__ Wq, const float* __restrict__ Wk,
    const float* __restrict__ Wv, const float* __restrict__ Wo,
    const float* __restrict__ W1, const float* __restrict__ W2,
    const float* __restrict__ bq, const float* __restrict__ bk,
    const float* __restrict__ bv,
    const float* __restrict__ bias, const int* __restrict__ mask,
    ushort* __restrict__ Wqkvb, ushort* __restrict__ Wob,
    ushort* __restrict__ W1b, ushort* __restrict__ W2b,
    float* __restrict__ bqkv, float* __restrict__ bM4) {
  int idx = blockIdx.x * 256 + threadIdx.x;
  if (idx < 49152) {                             // Wqkv: 768x256
    int e = idx * 4; int n = e >> 8; int k = e & 255;
    const float* src = n < 256 ? &Wq[n*256 + k]
                     : n < 512 ? &Wk[(n-256)*256 + k]
                               : &Wv[(n-512)*256 + k];
    float4 f = *(const float4*)src;
    ushort4 o = { f2bf(f.x), f2bf(f.y), f2bf(f.z), f2bf(f.w) };
    *(ushort4*)&Wqkvb[e] = o;
  } else if (idx < 65536) {                      // Wo: 256x256
    int e = (idx - 49152) * 4;
    float4 f = *(const float4*)&Wo[e];
    ushort4 o = { f2bf(f.x), f2bf(f.y), f2bf(f.z), f2bf(f.w) };
    *(ushort4*)&Wob[e] = o;
  } else if (idx < 98304) {                      // W1: 512x256
    int e = (idx - 65536) * 4;
    float4 f = *(const float4*)&W1[e];
    ushort4 o = { f2bf(f.x), f2bf(f.y), f2bf(f.z), f2bf(f.w) };
    *(ushort4*)&W1b[e] = o;
  } else if (idx < 131072) {                     // W2: 256x512
    int e = (idx - 98304) * 4;
    float4 f = *(const float4*)&W2[e];
    ushort4 o = { f2bf(f.x), f2bf(f.y), f2bf(f.z), f2bf(f.w) };
    *(ushort4*)&W2b[e] = o;
  } else if (idx < 262144) {                     // bM4[h][qb][c][h5][r4][q32][j]
    int eb = idx - 131072;
    int q32 = eb & 31, r4 = (eb >> 5) & 3, h5 = (eb >> 7) & 1;
    int c = (eb >> 8) & 7, qb = (eb >> 11) & 7, h = eb >> 14;
    int q = qb*32 + q32;
    int keyb = 32*c + 8*r4 + 4*h5;
    float4 b4 = *(const float4*)&bias[((size_t)(h*256 + q))*256 + keyb];
    int4   m4 = *(const int4*)&mask[(size_t)q*256 + keyb];
    float4 o;
    o.x = m4.x ? b4.x * LOG2E_ - 8.0f : -1e30f;
    o.y = m4.y ? b4.y * LOG2E_ - 8.0f : -1e30f;
    o.z = m4.z ? b4.z * LOG2E_ - 8.0f : -1e30f;
    o.w = m4.w ? b4.w * LOG2E_ - 8.0f : -1e30f;
    *(float4*)&bM4[(size_t)eb*4] = o;
  } else if (idx < 262336) {                     // bqkv: 768
    int e = (idx - 262144) * 4;
    const float* src = e < 256 ? &bq[e] : e < 512 ? &bk[e-256] : &bv[e-512];
    *(float4*)&bqkv[e] = *(const float4*)src;
  }
}

// ---------------- LayerNorm; TR=true writes j-major rows ---------------------
template<bool TR>
__global__ __launch_bounds__(256) void ln_k(const float* __restrict__ in,
    const float* __restrict__ g, const float* __restrict__ b,
    ushort* __restrict__ out) {
  int wid = threadIdx.x >> 6, lane = threadIdx.x & 63;
  size_t row = (size_t)blockIdx.x * 4 + wid;
  const float* x = in + row * C_;
  float4 v = *(const float4*)&x[lane*4];
  float s  = v.x + v.y + v.z + v.w;
  float s2 = v.x*v.x + v.y*v.y + v.z*v.z + v.w*v.w;
  #pragma unroll
  for (int off = 1; off < 64; off <<= 1) {
    s  += __shfl_xor(s,  off);
    s2 += __shfl_xor(s2, off);
  }
  float mean = s * (1.0f/C_);
  float var  = s2 * (1.0f/C_) - mean*mean;
  float inv  = rsqrtf(var + 1e-5f);
  float4 gg = *(const float4*)&g[lane*4];
  float4 bb = *(const float4*)&b[lane*4];
  ushort4 o;
  o.x = f2bf((v.x-mean)*inv*gg.x + bb.x);
  o.y = f2bf((v.y-mean)*inv*gg.y + bb.y);
  o.z = f2bf((v.z-mean)*inv*gg.z + bb.z);
  o.w = f2bf((v.w-mean)*inv*gg.w + bb.w);
  size_t orow = TR ? ((row & 255) * 256 + (row >> 8)) : row;
  *(ushort4*)&out[orow*C_ + lane*4] = o;
}

// ---------------- bf16 MFMA NT GEMM: BK=64, swizzled LDS ---------------------
// bf16 outputs (QKV / plain OUTBF16) go through an LDS-transpose epilogue so
// each lane stores 16B and waves emit full-cache-line runs.
// ADD: fp32 residual; ADDB: bf16 residual. R/Optr NOT restrict-qualified.
template<bool OUTBF16, bool RELU, bool ADD, bool ADDB, bool QKV>
__global__ __launch_bounds__(256) void gemm5(
    const ushort* __restrict__ A, const ushort* __restrict__ W,
    const float* __restrict__ bias, const void* Rp,
    void* Optr, int N, int K, int lda, int ldo, int nby) {
  __shared__ __align__(16) ushort LDSb[2][128][64];   // As=LDSb[0], Bs=LDSb[1]
  constexpr bool LDST = QKV || (OUTBF16 && !ADD && !ADDB);
  int f = blockIdx.x;
  int sw = (f & 7) * (gridDim.x >> 3) + (f >> 3);   // XCD-bijective (grid%8==0)
  const int bm = (sw / nby) * 128;
  const int bn = (sw % nby) * 128;
  const int t  = threadIdx.x;
  const int lane = t & 63, w = t >> 6;
  const int wm = (w >> 1) * 64, wn = (w & 1) * 64;
  const int lg = lane >> 4, lc = lane & 15;
  const int srow0 = t >> 3;          // 0..31
  const int scc   = t & 7;           // 16B chunk index

  v4f acc[4][4];
  #pragma unroll
  for (int i = 0; i < 4; ++i)
    #pragma unroll
    for (int jj = 0; jj < 4; ++jj) acc[i][jj] = (v4f){0.f,0.f,0.f,0.f};

  for (int k0 = 0; k0 < K; k0 += 64) {
    // stage: LDS[row][cc] <- global chunk (cc ^ (row&7))  [involution]
    #pragma unroll
    for (int s = 0; s < 4; ++s) {
      int row = s*32 + srow0;
      int gc  = (scc ^ (row & 7)) * 8;
      gload16(&A[(size_t)(bm + row)*lda + k0 + gc], (char*)LDSb + s*4096 + t*16);
      gload16(&W[(size_t)(bn + row)*K  + k0 + gc], (char*)LDSb + 16384 + s*4096 + t*16);
    }
    __syncthreads();
    #pragma unroll
    for (int kh = 0; kh < 2; ++kh) {
      v8s af[4], bf_[4];
      #pragma unroll
      for (int mi = 0; mi < 4; ++mi) {
        int row = wm + mi*16 + lc;
        int cd  = ((kh*4 + lg) ^ (row & 7)) * 16;
        af[mi] = *(const v8s*)((const char*)LDSb + row*128 + cd);
      }
      #pragma unroll
      for (int ni = 0; ni < 4; ++ni) {
        int row = wn + ni*16 + lc;
        int cd  = ((kh*4 + lg) ^ (row & 7)) * 16;
        bf_[ni] = *(const v8s*)((const char*)LDSb + 16384 + row*128 + cd);
      }
      // swapped operands: D row-index <- W (n), col-index <- A (m)
      #pragma unroll
      for (int mi = 0; mi < 4; ++mi)
        #pragma unroll
        for (int ni = 0; ni < 4; ++ni)
          acc[mi][ni] = __builtin_amdgcn_mfma_f32_16x16x32_bf16(bf_[ni], af[mi], acc[mi][ni], 0, 0, 0);
    }
    __syncthreads();
  }
  // epilogue: lane owns O[m = bm+wm+mi*16+lc][n0 .. n0+3], n0 = bn+wn+ni*16+lg*4
  if (LDST) {
    // stage bf16 tile in LDS (XOR-swizzled), then 16B/lane coalesced stores
    ushort* T = (ushort*)LDSb;   // [128][128]
    #pragma unroll
    for (int mi = 0; mi < 4; ++mi) {
      int row = wm + mi*16 + lc;
      #pragma unroll
      for (int ni = 0; ni < 4; ++ni) {
        int col = wn + ni*16 + lg*4;
        float4 bv = *(const float4*)&bias[bn + col];
        float o0 = acc[mi][ni][0] + bv.x;
        float o1 = acc[mi][ni][1] + bv.y;
        float o2 = acc[mi][ni][2] + bv.z;
        float o3 = acc[mi][ni][3] + bv.w;
        if (RELU) {
          o0 = fmaxf(o0, 0.f); o1 = fmaxf(o1, 0.f);
          o2 = fmaxf(o2, 0.f); o3 = fmaxf(o3, 0.f);
        }
        uint2 pw;
        pw.x = cvtpk(o0, o1);
        pw.y = cvtpk(o2, o3);
        *(uint2*)&T[row*128 + (col ^ ((row & 7) << 3))] = pw;
      }
    }
    __syncthreads();
    #pragma unroll
    for (int rr = 0; rr < 8; ++rr) {
      int row = rr*16 + (t >> 4);
      int cc  = t & 15;
      int sc  = cc ^ (row & 7);
      v8s vv = *(const v8s*)&T[row*128 + sc*8];
      if (QKV) {
        int m = bm + row;                           // j-major A rows
        int jj = m >> 8, i = m & 255;
        int n = bn + cc*8;
        int c = n & 255, proj = n >> 8;
        int hh = c >> 5, dd = c & 31;
        size_t idx = (size_t)proj*16777216 + (((size_t)hh*256 + jj)*256 + i)*32 + dd;
        *(v8s*)&((ushort*)Optr)[idx] = vv;
      } else {
        *(v8s*)&((ushort*)Optr)[(size_t)(bm + row)*ldo + bn + cc*8] = vv;
      }
    }
  } else {
    #pragma unroll
    for (int mi = 0; mi < 4; ++mi) {
      int m = bm + wm + mi*16 + lc;
      #pragma unroll
      for (int ni = 0; ni < 4; ++ni) {
        int n0 = bn + wn + ni*16 + lg*4;
        float4 bv = *(const float4*)&bias[n0];
        float o0 = acc[mi][ni][0] + bv.x;
        float o1 = acc[mi][ni][1] + bv.y;
        float o2 = acc[mi][ni][2] + bv.z;
        float o3 = acc[mi][ni][3] + bv.w;
        if (RELU) {
          o0 = fmaxf(o0, 0.f); o1 = fmaxf(o1, 0.f);
          o2 = fmaxf(o2, 0.f); o3 = fmaxf(o3, 0.f);
        }
        size_t idx = (size_t)m * ldo + n0;
        if (ADD) {
          float4 r4 = *(const float4*)&((const float*)Rp)[idx];
          o0 += r4.x; o1 += r4.y; o2 += r4.z; o3 += r4.w;
        }
        if (ADDB) {
          uint2 rb = *(const uint2*)&((const ushort*)Rp)[idx];
          o0 += bf2f((ushort)(rb.x & 0xFFFF));
          o1 += bf2f((ushort)(rb.x >> 16));
          o2 += bf2f((ushort)(rb.y & 0xFFFF));
          o3 += bf2f((ushort)(rb.y >> 16));
        }
        if (OUTBF16) {
          uint2 pr;
          pr.x = cvtpk(o0, o1);
          pr.y = cvtpk(o2, o3);
          *(uint2*)&((ushort*)Optr)[idx] = pr;
        } else {
          float4 so = {o0, o1, o2, o3};
          *(float4*)&((float*)Optr)[idx] = so;
        }
      }
    }
  }
}

// ---------------- fused Wo-GEMM + residual + LN2 (bf16 pr out, in-place) -----
__global__ __launch_bounds__(512) void wo_ln_k(
    const ushort* A, const ushort* __restrict__ W,
    const float* __restrict__ bo, const float* __restrict__ R,
    ushort* prb,
    const float* __restrict__ g2, const float* __restrict__ be2,
    ushort* __restrict__ yb) {
  __shared__ __align__(16) ushort As[128][64];   // 16KB
  __shared__ __align__(16) ushort Bs[256][64];   // 32KB
  int f = blockIdx.x;
  int sw = (f & 7) * (gridDim.x >> 3) + (f >> 3);   // grid=512, %8==0
  const int bm = sw * 128;
  const int t  = threadIdx.x;
  const int lane = t & 63, w = t >> 6;              // w 0..7
  const int wm = (w >> 2) * 64, wn = (w & 3) * 64;  // 2m x 4n waves
  const int lg = lane >> 4, lc = lane & 15;
  const int srow0 = t >> 3;          // 0..63
  const int scc   = t & 7;           // 16B chunk index

  v4f acc[4][4];
  #pragma unroll
  for (int i = 0; i < 4; ++i)
    #pragma unroll
    for (int jj = 0; jj < 4; ++jj) acc[i][jj] = (v4f){0.f,0.f,0.f,0.f};

  for (int k0 = 0; k0 < 256; k0 += 64) {
    #pragma unroll
    for (int s = 0; s < 2; ++s) {                   // A: 128 rows
      int row = s*64 + srow0;
      int gc  = (scc ^ (row & 7)) * 8;
      gload16(&A[(size_t)(bm + row)*256 + k0 + gc], (char*)As + s*8192 + t*16);
    }
    #pragma unroll
    for (int s = 0; s < 4; ++s) {                   // W: 256 rows (all of Wo)
      int row = s*64 + srow0;
      int gc  = (scc ^ (row & 7)) * 8;
      gload16(&W[(size_t)row*256 + k0 + gc], (char*)Bs + s*8192 + t*16);
    }
    __syncthreads();
    #pragma unroll
    for (int kh = 0; kh < 2; ++kh) {
      v8s af[4], bf_[4];
      #pragma unroll
      for (int mi = 0; mi < 4; ++mi) {
        int row = wm + mi*16 + lc;
        int cd  = ((kh*4 + lg) ^ (row & 7)) * 16;
        af[mi] = *(const v8s*)((const char*)As + row*128 + cd);
      }
      #pragma unroll
      for (int ni = 0; ni < 4; ++ni) {
        int row = wn + ni*16 + lc;
        int cd  = ((kh*4 + lg) ^ (row & 7)) * 16;
        bf_[ni] = *(const v8s*)((const char*)Bs + row*128 + cd);
      }
      #pragma unroll
      for (int mi = 0; mi < 4; ++mi)
        #pragma unroll
        for (int ni = 0; ni < 4; ++ni)
          acc[mi][ni] = __builtin_amdgcn_mfma_f32_16x16x32_bf16(bf_[ni], af[mi], acc[mi][ni], 0, 0, 0);
    }
    __syncthreads();   // after final iter: all LDS reads drained -> As reusable
  }

  // pr into acc (+ write bf16 prb in-place) + per-lane row partial sums
  float sum_mi[4], ssq_mi[4];
  #pragma unroll
  for (int mi = 0; mi < 4; ++mi) {
    int m = bm + wm + mi*16 + lc;
    float sm = 0.f, sq = 0.f;
    #pragma unroll
    for (int ni = 0; ni < 4; ++ni) {
      int n0 = wn + ni*16 + lg*4;
      float4 bv = *(const float4*)&bo[n0];
      float4 r4 = *(const float4*)&R[(size_t)m*256 + n0];
      float p0 = acc[mi][ni][0] + bv.x + r4.x;
      float p1 = acc[mi][ni][1] + bv.y + r4.y;
      float p2 = acc[mi][ni][2] + bv.z + r4.z;
      float p3 = acc[mi][ni][3] + bv.w + r4.w;
      acc[mi][ni][0] = p0; acc[mi][ni][1] = p1;
      acc[mi][ni][2] = p2; acc[mi][ni][3] = p3;
      uint2 pw;
      pw.x = cvtpk(p0, p1);
      pw.y = cvtpk(p2, p3);
      *(uint2*)&prb[(size_t)m*256 + n0] = pw;
      sm += (p0 + p1) + (p2 + p3);
      sq += (p0*p0 + p1*p1) + (p2*p2 + p3*p3);
    }
    sum_mi[mi] = sm; ssq_mi[mi] = sq;
  }
  // reduce over lg (xor 16, 32): per-wave 64-col partials
  #pragma unroll
  for (int mi = 0; mi < 4; ++mi) {
    sum_mi[mi] += __shfl_xor(sum_mi[mi], 16);
    sum_mi[mi] += __shfl_xor(sum_mi[mi], 32);
    ssq_mi[mi] += __shfl_xor(ssq_mi[mi], 16);
    ssq_mi[mi] += __shfl_xor(ssq_mi[mi], 32);
  }
  // cross-wave combine via LDS (reuse As: sum [0..512), sumsq [512..1024))
  float* sbuf = (float*)As;
  if (lg == 0) {
    #pragma unroll
    for (int mi = 0; mi < 4; ++mi) {
      int idx = w*64 + mi*16 + lc;
      sbuf[idx]       = sum_mi[mi];
      sbuf[512 + idx] = ssq_mi[mi];
    }
  }
  __syncthreads();
  #pragma unroll
  for (int mi = 0; mi < 4; ++mi) {
    int bi = (w >> 2)*256 + mi*16 + lc;   // (wm-half)*4 waves * 64
    float s = (sbuf[bi] + sbuf[bi+64]) + (sbuf[bi+128] + sbuf[bi+192]);
    float q = (sbuf[512+bi] + sbuf[512+bi+64]) + (sbuf[512+bi+128] + sbuf[512+bi+192]);
    float mu  = s * (1.0f/256.0f);
    float inv = rsqrtf(q * (1.0f/256.0f) - mu*mu + 1e-5f);
    int m = bm + wm + mi*16 + lc;
    #pragma unroll
    for (int ni = 0; ni < 4; ++ni) {
      int n0 = wn + ni*16 + lg*4;
      float4 gg = *(const float4*)&g2[n0];
      float4 bb = *(const float4*)&be2[n0];
      float y0 = (acc[mi][ni][0] - mu)*inv*gg.x + bb.x;
      float y1 = (acc[mi][ni][1] - mu)*inv*gg.y + bb.y;
      float y2 = (acc[mi][ni][2] - mu)*inv*gg.z + bb.z;
      float y3 = (acc[mi][ni][3] - mu)*inv*gg.w + bb.w;
      uint2 pr;
      pr.x = cvtpk(y0, y1);
      pr.y = cvtpk(y2, y3);
      *(uint2*)&yb[(size_t)m*256 + n0] = pr;
    }
  }
}

// ---------------- attention per (j,h): K+V both in LDS -----------------------
// r18 attn8 structure (fixed-shift softmax, cvt_pk, permlane PV) with K now
// staged in LDS (pad-36 rows -> 2-way banks on b128 reads = free). Removes
// the global K load from the QK^T critical path and frees L1 for Q/bias.
__global__ __launch_bounds__(256, 4) void attn10(
    const ushort* __restrict__ qt, const ushort* __restrict__ kt,
    const ushort* __restrict__ vt, const float* __restrict__ bM4,
    ushort* __restrict__ ao) {
  __shared__ __align__(16) ushort Vt[32][264];    // [d][key]   16.9KB
  __shared__ __align__(16) ushort Ks[256][36];    // [key][d]   18.4KB pad-36
  const int j = blockIdx.x & 255, h = blockIdx.x >> 8;
  const int t = threadIdx.x, w = t >> 6, lane = t & 63;
  const int l5 = lane & 31, h5 = lane >> 5;
  const size_t base = ((size_t)(h*256 + j)) * 8192;

  {
    // V transposed (thread = 4 keys x 8 d)
    const ushort* vsrc = vt + base;
    int k4 = (t & 63) * 4, sd = (t >> 6) * 8;
    v8s v0 = *(const v8s*)&vsrc[(k4+0)*32 + sd];
    v8s v1 = *(const v8s*)&vsrc[(k4+1)*32 + sd];
    v8s v2 = *(const v8s*)&vsrc[(k4+2)*32 + sd];
    v8s v3 = *(const v8s*)&vsrc[(k4+3)*32 + sd];
    #pragma unroll
    for (int u = 0; u < 8; ++u) {
      ushort4 q4 = { (ushort)v0[u], (ushort)v1[u], (ushort)v2[u], (ushort)v3[u] };
      *(ushort4*)&Vt[sd+u][k4] = q4;
    }
    // K rows: thread t stages 16B chunk per pass (contiguous global reads)
    const ushort* ksrcg = kt + base;
    #pragma unroll
    for (int s = 0; s < 4; ++s) {
      int el = s*2048 + t*8;               // element index (8 ushorts)
      v8s kv = *(const v8s*)&ksrcg[el];
      *(v8s*)&Ks[el >> 5][el & 31] = kv;   // row = el/32, col = el%32
    }
  }
  __syncthreads();   // only barrier

  const ushort* qsrc = qt + base;

  #pragma unroll 1
  for (int qi = 0; qi < 2; ++qi) {
    const int qb = w*2 + qi;
    v8s qf0 = *(const v8s*)&qsrc[(qb*32 + l5)*32 + h5*8];
    v8s qf1 = *(const v8s*)&qsrc[(qb*32 + l5)*32 + 16 + h5*8];
    const float* bqb = bM4 + (size_t)(h*8 + qb) * 8192;
    v16f o = Z16;
    float l = 0.f;

    #pragma unroll 2
    for (int c = 0; c < 8; ++c) {
      v8s kf0 = *(const v8s*)&Ks[c*32 + l5][h5*8];
      v8s kf1 = *(const v8s*)&Ks[c*32 + l5][16 + h5*8];
      v16f s = __builtin_amdgcn_mfma_f32_32x32x16_bf16(kf0, qf0, Z16, 0, 0, 0);
      s = __builtin_amdgcn_mfma_f32_32x32x16_bf16(kf1, qf1, s, 0, 0, 0);
      // p = exp2(s*scale + shifted bias); accumulate l; pack pairs via cvt_pk
      float p[16];
      #pragma unroll
      for (int r4 = 0; r4 < 4; ++r4) {
        float4 b4 = *(const float4*)&bqb[((c*2 + h5)*4 + r4)*128 + l5*4];
        p[r4*4+0] = __builtin_amdgcn_exp2f(fmaf(s[r4*4+0], SCALE2_, b4.x));
        p[r4*4+1] = __builtin_amdgcn_exp2f(fmaf(s[r4*4+1], SCALE2_, b4.y));
        p[r4*4+2] = __builtin_amdgcn_exp2f(fmaf(s[r4*4+2], SCALE2_, b4.z));
        p[r4*4+3] = __builtin_amdgcn_exp2f(fmaf(s[r4*4+3], SCALE2_, b4.w));
      }
      #pragma unroll
      for (int r = 0; r < 16; ++r) l += p[r];
      uint pk[8];
      #pragma unroll
      for (int i2 = 0; i2 < 8; ++i2)
        pk[i2] = cvtpk(p[2*i2], p[2*i2+1]);
      uint w0 = pk[0], w2 = pk[2]; pl32swap(w0, w2);
      uint w1 = pk[1], w3 = pk[3]; pl32swap(w1, w3);
      uint w4 = pk[4], w6 = pk[6]; pl32swap(w4, w6);
      uint w5 = pk[5], w7 = pk[7]; pl32swap(w5, w7);
      uint4 B1 = {w0, w1, w2, w3};
      uint4 B2 = {w4, w5, w6, w7};
      v8s vv1 = *(const v8s*)&Vt[l5][c*32 + h5*8];
      v8s vv2 = *(const v8s*)&Vt[l5][c*32 + 16 + h5*8];
      o = __builtin_amdgcn_mfma_f32_32x32x16_bf16(vv1, *(v8s*)&B1, o, 0, 0, 0);
      o = __builtin_amdgcn_mfma_f32_32x32x16_bf16(vv2, *(v8s*)&B2, o, 0, 0, 0);
    }
    float lt = l + __shfl_xor(l, 32);
    float inv = 1.0f / lt;
    size_t ob = ((size_t)(qb*32 + l5)*256 + j)*256 + h*32;
    #pragma unroll
    for (int r4 = 0; r4 < 4; ++r4) {
      uint2 pr;
      pr.x = cvtpk(o[4*r4+0]*inv, o[4*r4+1]*inv);
      pr.y = cvtpk(o[4*r4+2]*inv, o[4*r4+3]*inv);
      *(uint2*)&ao[ob + 8*r4 + 4*h5] = pr;
    }
  }
}

extern "C" void kernel_launch(void* const* d_in, const int* in_sizes, int n_in,
                              void* d_out, int out_size, void* d_ws, size_t ws_size,
                              hipStream_t stream) {
  const float* pair_repr = (const float*)d_in[0];
  const float* pair_bias = (const float*)d_in[1];
  const float* Wq = (const float*)d_in[2];
  const float* bq = (const float*)d_in[3];
  const float* Wk = (const float*)d_in[4];
  const float* bk = (const float*)d_in[5];
  const float* Wv = (const float*)d_in[6];
  const float* bv = (const float*)d_in[7];
  const float* Wo = (const float*)d_in[8];
  const float* bo = (const float*)d_in[9];
  const float* W1 = (const float*)d_in[10];
  const float* b1 = (const float*)d_in[11];
  const float* W2 = (const float*)d_in[12];
  const float* b2 = (const float*)d_in[13];
  const float* g1 = (const float*)d_in[14];
  const float* be1= (const float*)d_in[15];
  const float* g2 = (const float*)d_in[16];
  const float* be2= (const float*)d_in[17];
  const int* mask = (const int*)d_in[18];
  float* out = (float*)d_out;

  char* wsb = (char*)d_ws;
  ushort* xb = (ushort*)wsb;                    // region A: LN1 out -> ao -> prb
  ushort* ao = (ushort*)wsb;
  ushort* prb = (ushort*)wsb;                   // pr bf16, in-place over ao
  ushort* qt = (ushort*)(wsb + 33554432);       // region B: q_t -> yb
  ushort* yb = qt;
  ushort* kt = (ushort*)(wsb + 67108864);       // region C: k_t, v_t -> hb
  ushort* vt = (ushort*)(wsb + 100663296);
  ushort* hb = kt;
  char* d0 = wsb + 134217728;                   // region D: weights/bias
  ushort* Wqkvb = (ushort*)d0;
  ushort* Wob   = (ushort*)(d0 + 393216);
  ushort* W1b   = (ushort*)(d0 + 524288);
  ushort* W2b   = (ushort*)(d0 + 786432);
  float*  bqkv  = (float*)(d0 + 1048576);
  float*  bM4   = (float*)(d0 + 1052672);

  // 0. prep
  prep_k<<<dim3(1025), 256, 0, stream>>>(Wq, Wk, Wv, Wo, W1, W2, bq, bk, bv,
                                         pair_bias, mask, Wqkvb, Wob, W1b, W2b, bqkv, bM4);
  // 1. x = LN1(pair_repr) -> xb (j-major rows)
  ln_k<true><<<dim3(M_/4), 256, 0, stream>>>(pair_repr, g1, be1, xb);
  // 2. qkv projection -> head-major qt/kt/vt (LDS-transpose coalesced stores)
  gemm5<true,false,false,false,true><<<dim3(3072), 256, 0, stream>>>(
      xb, Wqkvb, bqkv, nullptr, (void*)qt, 768, C_, C_, 0, 6);
  // 3. attention -> ao (region A; xb dead)
  attn10<<<dim3(L_*H_), 256, 0, stream>>>(qt, kt, vt, bM4, ao);
  // 4+5. pr(bf16) = ao@Wo.T + bo + pair_repr -> prb (in-place); y = LN2 -> yb
  wo_ln_k<<<dim3(512), 512, 0, stream>>>(ao, Wob, bo, pair_repr, prb, g2, be2, yb);
  // 6. h = relu(y@W1.T + b1) -> hb (LDS-transpose coalesced stores)
  gemm5<true,true,false,false,false><<<dim3(2048), 256, 0, stream>>>(
      yb, W1b, b1, nullptr, (void*)hb, F_, C_, C_, F_, 4);
  // 7. out = prb + h@W2.T + b2 -> d_out (fp32, sole writer of out)
  gemm5<false,false,false,true,false><<<dim3(1024), 256, 0, stream>>>(
      hb, W2b, b2, prb, out, C_, F_, F_, C_, 2);
}

// Round 22
// 197.810 us; speedup vs baseline: 1.1744x; 1.0825x over previous
//
#include <hip/hip_runtime.h>

#define L_ 256
#define C_ 256
#define H_ 8
#define D_ 32
#define F_ 512
#define M_ (L_*L_)   // 65536 rows
#define SCALE2_ 0.2550348564624926f   // (1/sqrt(32)) * log2(e)
#define LOG2E_  1.4426950408889634f

typedef __attribute__((ext_vector_type(8))) short v8s;    // 8 bf16 = 16B
typedef __attribute__((ext_vector_type(4))) float v4f;    // 16x16 MFMA acc
typedef __attribute__((ext_vector_type(16))) float v16f;  // 32x32 MFMA acc
#define Z16 (v16f){0,0,0,0,0,0,0,0,0,0,0,0,0,0,0,0}

__device__ __forceinline__ ushort f2bf(float f) {
  union { float f; unsigned u; } v; v.f = f;
  unsigned r = v.u + 0x7FFFu + ((v.u >> 16) & 1u);   // RNE
  return (ushort)(r >> 16);
}

__device__ __forceinline__ float bf2f(ushort u) {
  union { unsigned u; float f; } v; v.u = (unsigned)u << 16;
  return v.f;
}

// pack 2 fp32 -> 2 bf16 in one instr (RNE); lo -> bits 0-15
__device__ __forceinline__ uint cvtpk(float lo, float hi) {
  uint r;
  asm("v_cvt_pk_bf16_f32 %0, %1, %2" : "=v"(r) : "v"(lo), "v"(hi));
  return r;
}

__device__ __forceinline__ void gload16(const void* g, void* l) {
  __builtin_amdgcn_global_load_lds(
      (const __attribute__((address_space(1))) void*)g,
      (__attribute__((address_space(3))) void*)l, 16, 0, 0);
}

// half-exchange: a' = [a.lo | b.lo], b' = [a.hi | b.hi]
__device__ __forceinline__ void pl32swap(uint &a, uint &b) {
  asm volatile("v_permlane32_swap_b32 %0, %1" : "+v"(a), "+v"(b));
}

// ---------------- prep: weights -> bf16, bias retile for 32x32 path ----------
// bM4 entries carry the fixed softmax shift: b*log2e - 8 (softmax is
// shift-invariant; bf16/fp32 share exponent range so no stability cost).
__global__ __launch_bounds__(256) void prep_k(
    const float* __restrict__ Wq, const float* __restrict__ Wk,
    const float* __restrict__ Wv, const float* __restrict__ Wo,
    const float* __restrict__ W1, const float* __restrict__ W2,
    const float* __restrict__ bq, const float* __restrict__ bk,
    const float* __restrict__ bv,
    const float* __restrict__ bias, const int* __restrict__ mask,
    ushort* __restrict__ Wqkvb, ushort* __restrict__ Wob,
    ushort* __restrict__ W1b, ushort* __restrict__ W2b,
    float* __restrict__ bqkv, float* __restrict__ bM4) {
  int idx = blockIdx.x * 256 + threadIdx.x;
  if (idx < 49152) {                             // Wqkv: 768x256
    int e = idx * 4; int n = e >> 8; int k = e & 255;
    const float* src = n < 256 ? &Wq[n*256 + k]
                     : n < 512 ? &Wk[(n-256)*256 + k]
                               : &Wv[(n-512)*256 + k];
    float4 f = *(const float4*)src;
    ushort4 o = { f2bf(f.x), f2bf(f.y), f2bf(f.z), f2bf(f.w) };
    *(ushort4*)&Wqkvb[e] = o;
  } else if (idx < 65536) {                      // Wo: 256x256
    int e = (idx - 49152) * 4;
    float4 f = *(const float4*)&Wo[e];
    ushort4 o = { f2bf(f.x), f2bf(f.y), f2bf(f.z), f2bf(f.w) };
    *(ushort4*)&Wob[e] = o;
  } else if (idx < 98304) {                      // W1: 512x256
    int e = (idx - 65536) * 4;
    float4 f = *(const float4*)&W1[e];
    ushort4 o = { f2bf(f.x), f2bf(f.y), f2bf(f.z), f2bf(f.w) };
    *(ushort4*)&W1b[e] = o;
  } else if (idx < 131072) {                     // W2: 256x512
    int e = (idx - 98304) * 4;
    float4 f = *(const float4*)&W2[e];
    ushort4 o = { f2bf(f.x), f2bf(f.y), f2bf(f.z), f2bf(f.w) };
    *(ushort4*)&W2b[e] = o;
  } else if (idx < 262144) {                     // bM4[h][qb][c][h5][r4][q32][j]
    int eb = idx - 131072;
    int q32 = eb & 31, r4 = (eb >> 5) & 3, h5 = (eb >> 7) & 1;
    int c = (eb >> 8) & 7, qb = (eb >> 11) & 7, h = eb >> 14;
    int q = qb*32 + q32;
    int keyb = 32*c + 8*r4 + 4*h5;
    float4 b4 = *(const float4*)&bias[((size_t)(h*256 + q))*256 + keyb];
    int4   m4 = *(const int4*)&mask[(size_t)q*256 + keyb];
    float4 o;
    o.x = m4.x ? b4.x * LOG2E_ - 8.0f : -1e30f;
    o.y = m4.y ? b4.y * LOG2E_ - 8.0f : -1e30f;
    o.z = m4.z ? b4.z * LOG2E_ - 8.0f : -1e30f;
    o.w = m4.w ? b4.w * LOG2E_ - 8.0f : -1e30f;
    *(float4*)&bM4[(size_t)eb*4] = o;
  } else if (idx < 262336) {                     // bqkv: 768
    int e = (idx - 262144) * 4;
    const float* src = e < 256 ? &bq[e] : e < 512 ? &bk[e-256] : &bv[e-512];
    *(float4*)&bqkv[e] = *(const float4*)src;
  }
}

// ---------------- LayerNorm; TR=true writes j-major rows ---------------------
template<bool TR>
__global__ __launch_bounds__(256) void ln_k(const float* __restrict__ in,
    const float* __restrict__ g, const float* __restrict__ b,
    ushort* __restrict__ out) {
  int wid = threadIdx.x >> 6, lane = threadIdx.x & 63;
  size_t row = (size_t)blockIdx.x * 4 + wid;
  const float* x = in + row * C_;
  float4 v = *(const float4*)&x[lane*4];
  float s  = v.x + v.y + v.z + v.w;
  float s2 = v.x*v.x + v.y*v.y + v.z*v.z + v.w*v.w;
  #pragma unroll
  for (int off = 1; off < 64; off <<= 1) {
    s  += __shfl_xor(s,  off);
    s2 += __shfl_xor(s2, off);
  }
  float mean = s * (1.0f/C_);
  float var  = s2 * (1.0f/C_) - mean*mean;
  float inv  = rsqrtf(var + 1e-5f);
  float4 gg = *(const float4*)&g[lane*4];
  float4 bb = *(const float4*)&b[lane*4];
  ushort4 o;
  o.x = f2bf((v.x-mean)*inv*gg.x + bb.x);
  o.y = f2bf((v.y-mean)*inv*gg.y + bb.y);
  o.z = f2bf((v.z-mean)*inv*gg.z + bb.z);
  o.w = f2bf((v.w-mean)*inv*gg.w + bb.w);
  size_t orow = TR ? ((row & 255) * 256 + (row >> 8)) : row;
  *(ushort4*)&out[orow*C_ + lane*4] = o;
}

// ---------------- bf16 MFMA NT GEMM: 128x256 tile, 512 threads ---------------
// wo_ln-proven loop structure (8 waves 2m x 4n, 48KB LDS -> 3 blocks/CU):
// halves A-staging + barriers per output byte vs the 128x128 tile.
// bf16 outputs go through a 2-half LDS-transpose epilogue (32KB T overlay).
// ADDB: bf16 residual. R/Optr NOT restrict-qualified.
template<bool OUTBF16, bool RELU, bool ADDB, bool QKV>
__global__ __launch_bounds__(512) void gemm6(
    const ushort* __restrict__ A, const ushort* __restrict__ W,
    const float* __restrict__ bias, const void* Rp,
    void* Optr, int N, int K, int lda, int ldo, int nby) {
  __shared__ __align__(16) ushort LDSb[384][64];   // A=rows0..127 (16KB), B=rows128..383 (32KB)
  constexpr bool LDST = QKV || (OUTBF16 && !ADDB);
  int f = blockIdx.x;
  int sw = (f & 7) * (gridDim.x >> 3) + (f >> 3);   // XCD-bijective (grid%8==0)
  const int bm = (sw / nby) * 128;
  const int bn = (sw % nby) * 256;
  const int t  = threadIdx.x;
  const int lane = t & 63, w = t >> 6;              // w 0..7
  const int wm = (w >> 2) * 64, wn = (w & 3) * 64;  // 2m x 4n waves
  const int lg = lane >> 4, lc = lane & 15;
  const int srow0 = t >> 3;          // 0..63
  const int scc   = t & 7;           // 16B chunk index

  v4f acc[4][4];
  #pragma unroll
  for (int i = 0; i < 4; ++i)
    #pragma unroll
    for (int jj = 0; jj < 4; ++jj) acc[i][jj] = (v4f){0.f,0.f,0.f,0.f};

  for (int k0 = 0; k0 < K; k0 += 64) {
    #pragma unroll
    for (int s = 0; s < 2; ++s) {                   // A: 128 rows
      int row = s*64 + srow0;
      int gc  = (scc ^ (row & 7)) * 8;
      gload16(&A[(size_t)(bm + row)*lda + k0 + gc], (char*)LDSb + s*8192 + t*16);
    }
    #pragma unroll
    for (int s = 0; s < 4; ++s) {                   // B: 256 rows
      int row = s*64 + srow0;
      int gc  = (scc ^ (row & 7)) * 8;
      gload16(&W[(size_t)(bn + row)*K + k0 + gc], (char*)LDSb + 16384 + s*8192 + t*16);
    }
    __syncthreads();
    #pragma unroll
    for (int kh = 0; kh < 2; ++kh) {
      v8s af[4], bf_[4];
      #pragma unroll
      for (int mi = 0; mi < 4; ++mi) {
        int row = wm + mi*16 + lc;
        int cd  = ((kh*4 + lg) ^ (row & 7)) * 16;
        af[mi] = *(const v8s*)((const char*)LDSb + row*128 + cd);
      }
      #pragma unroll
      for (int ni = 0; ni < 4; ++ni) {
        int row = wn + ni*16 + lc;
        int cd  = ((kh*4 + lg) ^ (row & 7)) * 16;
        bf_[ni] = *(const v8s*)((const char*)LDSb + 16384 + row*128 + cd);
      }
      // swapped operands: D row-index <- W (n), col-index <- A (m)
      #pragma unroll
      for (int mi = 0; mi < 4; ++mi)
        #pragma unroll
        for (int ni = 0; ni < 4; ++ni)
          acc[mi][ni] = __builtin_amdgcn_mfma_f32_16x16x32_bf16(bf_[ni], af[mi], acc[mi][ni], 0, 0, 0);
    }
    __syncthreads();
  }
  // epilogue: lane owns O[m = bm+wm+mi*16+lc][col .. col+3], col = wn+ni*16+lg*4
  if (LDST) {
    // two 128-col halves through a 32KB transpose buffer (overlays A+B LDS)
    ushort* T = (ushort*)LDSb;   // [128][128]
    #pragma unroll
    for (int nh = 0; nh < 2; ++nh) {
      if (((w & 3) >> 1) == nh) {
        #pragma unroll
        for (int mi = 0; mi < 4; ++mi) {
          int row = wm + mi*16 + lc;
          #pragma unroll
          for (int ni = 0; ni < 4; ++ni) {
            int col = wn + ni*16 + lg*4;            // 0..255; this wave's half
            float4 bv = *(const float4*)&bias[bn + col];
            float o0 = acc[mi][ni][0] + bv.x;
            float o1 = acc[mi][ni][1] + bv.y;
            float o2 = acc[mi][ni][2] + bv.z;
            float o3 = acc[mi][ni][3] + bv.w;
            if (RELU) {
              o0 = fmaxf(o0, 0.f); o1 = fmaxf(o1, 0.f);
              o2 = fmaxf(o2, 0.f); o3 = fmaxf(o3, 0.f);
            }
            uint2 pw;
            pw.x = cvtpk(o0, o1);
            pw.y = cvtpk(o2, o3);
            *(uint2*)&T[row*128 + ((col & 127) ^ ((row & 7) << 3))] = pw;
          }
        }
      }
      __syncthreads();
      #pragma unroll
      for (int rr = 0; rr < 4; ++rr) {
        int row = rr*32 + (t >> 4);
        int cc  = t & 15;
        int sc  = cc ^ (row & 7);
        v8s vv = *(const v8s*)&T[row*128 + sc*8];
        if (QKV) {
          int m = bm + row;                         // j-major A rows
          int jj = m >> 8, i = m & 255;
          int n = bn + nh*128 + cc*8;
          int c = n & 255, proj = n >> 8;
          int hh = c >> 5, dd = c & 31;
          size_t idx = (size_t)proj*16777216 + (((size_t)hh*256 + jj)*256 + i)*32 + dd;
          *(v8s*)&((ushort*)Optr)[idx] = vv;
        } else {
          *(v8s*)&((ushort*)Optr)[(size_t)(bm + row)*ldo + bn + nh*128 + cc*8] = vv;
        }
      }
      __syncthreads();
    }
  } else {
    #pragma unroll
    for (int mi = 0; mi < 4; ++mi) {
      int m = bm + wm + mi*16 + lc;
      #pragma unroll
      for (int ni = 0; ni < 4; ++ni) {
        int n0 = bn + wn + ni*16 + lg*4;
        float4 bv = *(const float4*)&bias[n0];
        float o0 = acc[mi][ni][0] + bv.x;
        float o1 = acc[mi][ni][1] + bv.y;
        float o2 = acc[mi][ni][2] + bv.z;
        float o3 = acc[mi][ni][3] + bv.w;
        if (RELU) {
          o0 = fmaxf(o0, 0.f); o1 = fmaxf(o1, 0.f);
          o2 = fmaxf(o2, 0.f); o3 = fmaxf(o3, 0.f);
        }
        size_t idx = (size_t)m * ldo + n0;
        if (ADDB) {
          uint2 rb = *(const uint2*)&((const ushort*)Rp)[idx];
          o0 += bf2f((ushort)(rb.x & 0xFFFF));
          o1 += bf2f((ushort)(rb.x >> 16));
          o2 += bf2f((ushort)(rb.y & 0xFFFF));
          o3 += bf2f((ushort)(rb.y >> 16));
        }
        if (OUTBF16) {
          uint2 pr;
          pr.x = cvtpk(o0, o1);
          pr.y = cvtpk(o2, o3);
          *(uint2*)&((ushort*)Optr)[idx] = pr;
        } else {
          float4 so = {o0, o1, o2, o3};
          *(float4*)&((float*)Optr)[idx] = so;
        }
      }
    }
  }
}

// ---------------- fused Wo-GEMM + residual + LN2 (bf16 pr out, in-place) -----
__global__ __launch_bounds__(512) void wo_ln_k(
    const ushort* A, const ushort* __restrict__ W,
    const float* __restrict__ bo, const float* __restrict__ R,
    ushort* prb,
    const float* __restrict__ g2, const float* __restrict__ be2,
    ushort* __restrict__ yb) {
  __shared__ __align__(16) ushort As[128][64];   // 16KB
  __shared__ __align__(16) ushort Bs[256][64];   // 32KB
  int f = blockIdx.x;
  int sw = (f & 7) * (gridDim.x >> 3) + (f >> 3);   // grid=512, %8==0
  const int bm = sw * 128;
  const int t  = threadIdx.x;
  const int lane = t & 63, w = t >> 6;              // w 0..7
  const int wm = (w >> 2) * 64, wn = (w & 3) * 64;  // 2m x 4n waves
  const int lg = lane >> 4, lc = lane & 15;
  const int srow0 = t >> 3;          // 0..63
  const int scc   = t & 7;           // 16B chunk index

  v4f acc[4][4];
  #pragma unroll
  for (int i = 0; i < 4; ++i)
    #pragma unroll
    for (int jj = 0; jj < 4; ++jj) acc[i][jj] = (v4f){0.f,0.f,0.f,0.f};

  for (int k0 = 0; k0 < 256; k0 += 64) {
    #pragma unroll
    for (int s = 0; s < 2; ++s) {                   // A: 128 rows
      int row = s*64 + srow0;
      int gc  = (scc ^ (row & 7)) * 8;
      gload16(&A[(size_t)(bm + row)*256 + k0 + gc], (char*)As + s*8192 + t*16);
    }
    #pragma unroll
    for (int s = 0; s < 4; ++s) {                   // W: 256 rows (all of Wo)
      int row = s*64 + srow0;
      int gc  = (scc ^ (row & 7)) * 8;
      gload16(&W[(size_t)row*256 + k0 + gc], (char*)Bs + s*8192 + t*16);
    }
    __syncthreads();
    #pragma unroll
    for (int kh = 0; kh < 2; ++kh) {
      v8s af[4], bf_[4];
      #pragma unroll
      for (int mi = 0; mi < 4; ++mi) {
        int row = wm + mi*16 + lc;
        int cd  = ((kh*4 + lg) ^ (row & 7)) * 16;
        af[mi] = *(const v8s*)((const char*)As + row*128 + cd);
      }
      #pragma unroll
      for (int ni = 0; ni < 4; ++ni) {
        int row = wn + ni*16 + lc;
        int cd  = ((kh*4 + lg) ^ (row & 7)) * 16;
        bf_[ni] = *(const v8s*)((const char*)Bs + row*128 + cd);
      }
      #pragma unroll
      for (int mi = 0; mi < 4; ++mi)
        #pragma unroll
        for (int ni = 0; ni < 4; ++ni)
          acc[mi][ni] = __builtin_amdgcn_mfma_f32_16x16x32_bf16(bf_[ni], af[mi], acc[mi][ni], 0, 0, 0);
    }
    __syncthreads();   // after final iter: all LDS reads drained -> As reusable
  }

  // pr into acc (+ write bf16 prb in-place) + per-lane row partial sums
  float sum_mi[4], ssq_mi[4];
  #pragma unroll
  for (int mi = 0; mi < 4; ++mi) {
    int m = bm + wm + mi*16 + lc;
    float sm = 0.f, sq = 0.f;
    #pragma unroll
    for (int ni = 0; ni < 4; ++ni) {
      int n0 = wn + ni*16 + lg*4;
      float4 bv = *(const float4*)&bo[n0];
      float4 r4 = *(const float4*)&R[(size_t)m*256 + n0];
      float p0 = acc[mi][ni][0] + bv.x + r4.x;
      float p1 = acc[mi][ni][1] + bv.y + r4.y;
      float p2 = acc[mi][ni][2] + bv.z + r4.z;
      float p3 = acc[mi][ni][3] + bv.w + r4.w;
      acc[mi][ni][0] = p0; acc[mi][ni][1] = p1;
      acc[mi][ni][2] = p2; acc[mi][ni][3] = p3;
      uint2 pw;
      pw.x = cvtpk(p0, p1);
      pw.y = cvtpk(p2, p3);
      *(uint2*)&prb[(size_t)m*256 + n0] = pw;
      sm += (p0 + p1) + (p2 + p3);
      sq += (p0*p0 + p1*p1) + (p2*p2 + p3*p3);
    }
    sum_mi[mi] = sm; ssq_mi[mi] = sq;
  }
  // reduce over lg (xor 16, 32): per-wave 64-col partials
  #pragma unroll
  for (int mi = 0; mi < 4; ++mi) {
    sum_mi[mi] += __shfl_xor(sum_mi[mi], 16);
    sum_mi[mi] += __shfl_xor(sum_mi[mi], 32);
    ssq_mi[mi] += __shfl_xor(ssq_mi[mi], 16);
    ssq_mi[mi] += __shfl_xor(ssq_mi[mi], 32);
  }
  // cross-wave combine via LDS (reuse As: sum [0..512), sumsq [512..1024))
  float* sbuf = (float*)As;
  if (lg == 0) {
    #pragma unroll
    for (int mi = 0; mi < 4; ++mi) {
      int idx = w*64 + mi*16 + lc;
      sbuf[idx]       = sum_mi[mi];
      sbuf[512 + idx] = ssq_mi[mi];
    }
  }
  __syncthreads();
  #pragma unroll
  for (int mi = 0; mi < 4; ++mi) {
    int bi = (w >> 2)*256 + mi*16 + lc;   // (wm-half)*4 waves * 64
    float s = (sbuf[bi] + sbuf[bi+64]) + (sbuf[bi+128] + sbuf[bi+192]);
    float q = (sbuf[512+bi] + sbuf[512+bi+64]) + (sbuf[512+bi+128] + sbuf[512+bi+192]);
    float mu  = s * (1.0f/256.0f);
    float inv = rsqrtf(q * (1.0f/256.0f) - mu*mu + 1e-5f);
    int m = bm + wm + mi*16 + lc;
    #pragma unroll
    for (int ni = 0; ni < 4; ++ni) {
      int n0 = wn + ni*16 + lg*4;
      float4 gg = *(const float4*)&g2[n0];
      float4 bb = *(const float4*)&be2[n0];
      float y0 = (acc[mi][ni][0] - mu)*inv*gg.x + bb.x;
      float y1 = (acc[mi][ni][1] - mu)*inv*gg.y + bb.y;
      float y2 = (acc[mi][ni][2] - mu)*inv*gg.z + bb.z;
      float y3 = (acc[mi][ni][3] - mu)*inv*gg.w + bb.w;
      uint2 pr;
      pr.x = cvtpk(y0, y1);
      pr.y = cvtpk(y2, y3);
      *(uint2*)&yb[(size_t)m*256 + n0] = pr;
    }
  }
}

// ---------------- attention per (j,h): K+V both in LDS (r21-exact) -----------
__global__ __launch_bounds__(256, 4) void attn10(
    const ushort* __restrict__ qt, const ushort* __restrict__ kt,
    const ushort* __restrict__ vt, const float* __restrict__ bM4,
    ushort* __restrict__ ao) {
  __shared__ __align__(16) ushort Vt[32][264];    // [d][key]   16.9KB
  __shared__ __align__(16) ushort Ks[256][36];    // [key][d]   18.4KB pad-36
  const int j = blockIdx.x & 255, h = blockIdx.x >> 8;
  const int t = threadIdx.x, w = t >> 6, lane = t & 63;
  const int l5 = lane & 31, h5 = lane >> 5;
  const size_t base = ((size_t)(h*256 + j)) * 8192;

  {
    // V transposed (thread = 4 keys x 8 d)
    const ushort* vsrc = vt + base;
    int k4 = (t & 63) * 4, sd = (t >> 6) * 8;
    v8s v0 = *(const v8s*)&vsrc[(k4+0)*32 + sd];
    v8s v1 = *(const v8s*)&vsrc[(k4+1)*32 + sd];
    v8s v2 = *(const v8s*)&vsrc[(k4+2)*32 + sd];
    v8s v3 = *(const v8s*)&vsrc[(k4+3)*32 + sd];
    #pragma unroll
    for (int u = 0; u < 8; ++u) {
      ushort4 q4 = { (ushort)v0[u], (ushort)v1[u], (ushort)v2[u], (ushort)v3[u] };
      *(ushort4*)&Vt[sd+u][k4] = q4;
    }
    // K rows: thread t stages 16B chunk per pass (contiguous global reads)
    const ushort* ksrcg = kt + base;
    #pragma unroll
    for (int s = 0; s < 4; ++s) {
      int el = s*2048 + t*8;               // element index (8 ushorts)
      v8s kv = *(const v8s*)&ksrcg[el];
      *(v8s*)&Ks[el >> 5][el & 31] = kv;   // row = el/32, col = el%32
    }
  }
  __syncthreads();   // only barrier

  const ushort* qsrc = qt + base;

  #pragma unroll 1
  for (int qi = 0; qi < 2; ++qi) {
    const int qb = w*2 + qi;
    v8s qf0 = *(const v8s*)&qsrc[(qb*32 + l5)*32 + h5*8];
    v8s qf1 = *(const v8s*)&qsrc[(qb*32 + l5)*32 + 16 + h5*8];
    const float* bqb = bM4 + (size_t)(h*8 + qb) * 8192;
    v16f o = Z16;
    float l = 0.f;

    #pragma unroll 2
    for (int c = 0; c < 8; ++c) {
      v8s kf0 = *(const v8s*)&Ks[c*32 + l5][h5*8];
      v8s kf1 = *(const v8s*)&Ks[c*32 + l5][16 + h5*8];
      v16f s = __builtin_amdgcn_mfma_f32_32x32x16_bf16(kf0, qf0, Z16, 0, 0, 0);
      s = __builtin_amdgcn_mfma_f32_32x32x16_bf16(kf1, qf1, s, 0, 0, 0);
      // p = exp2(s*scale + shifted bias); accumulate l; pack pairs via cvt_pk
      float p[16];
      #pragma unroll
      for (int r4 = 0; r4 < 4; ++r4) {
        float4 b4 = *(const float4*)&bqb[((c*2 + h5)*4 + r4)*128 + l5*4];
        p[r4*4+0] = __builtin_amdgcn_exp2f(fmaf(s[r4*4+0], SCALE2_, b4.x));
        p[r4*4+1] = __builtin_amdgcn_exp2f(fmaf(s[r4*4+1], SCALE2_, b4.y));
        p[r4*4+2] = __builtin_amdgcn_exp2f(fmaf(s[r4*4+2], SCALE2_, b4.z));
        p[r4*4+3] = __builtin_amdgcn_exp2f(fmaf(s[r4*4+3], SCALE2_, b4.w));
      }
      #pragma unroll
      for (int r = 0; r < 16; ++r) l += p[r];
      uint pk[8];
      #pragma unroll
      for (int i2 = 0; i2 < 8; ++i2)
        pk[i2] = cvtpk(p[2*i2], p[2*i2+1]);
      uint w0 = pk[0], w2 = pk[2]; pl32swap(w0, w2);
      uint w1 = pk[1], w3 = pk[3]; pl32swap(w1, w3);
      uint w4 = pk[4], w6 = pk[6]; pl32swap(w4, w6);
      uint w5 = pk[5], w7 = pk[7]; pl32swap(w5, w7);
      uint4 B1 = {w0, w1, w2, w3};
      uint4 B2 = {w4, w5, w6, w7};
      v8s vv1 = *(const v8s*)&Vt[l5][c*32 + h5*8];
      v8s vv2 = *(const v8s*)&Vt[l5][c*32 + 16 + h5*8];
      o = __builtin_amdgcn_mfma_f32_32x32x16_bf16(vv1, *(v8s*)&B1, o, 0, 0, 0);
      o = __builtin_amdgcn_mfma_f32_32x32x16_bf16(vv2, *(v8s*)&B2, o, 0, 0, 0);
    }
    float lt = l + __shfl_xor(l, 32);
    float inv = 1.0f / lt;
    size_t ob = ((size_t)(qb*32 + l5)*256 + j)*256 + h*32;
    #pragma unroll
    for (int r4 = 0; r4 < 4; ++r4) {
      uint2 pr;
      pr.x = cvtpk(o[4*r4+0]*inv, o[4*r4+1]*inv);
      pr.y = cvtpk(o[4*r4+2]*inv, o[4*r4+3]*inv);
      *(uint2*)&ao[ob + 8*r4 + 4*h5] = pr;
    }
  }
}

extern "C" void kernel_launch(void* const* d_in, const int* in_sizes, int n_in,
                              void* d_out, int out_size, void* d_ws, size_t ws_size,
                              hipStream_t stream) {
  const float* pair_repr = (const float*)d_in[0];
  const float* pair_bias = (const float*)d_in[1];
  const float* Wq = (const float*)d_in[2];
  const float* bq = (const float*)d_in[3];
  const float* Wk = (const float*)d_in[4];
  const float* bk = (const float*)d_in[5];
  const float* Wv = (const float*)d_in[6];
  const float* bv = (const float*)d_in[7];
  const float* Wo = (const float*)d_in[8];
  const float* bo = (const float*)d_in[9];
  const float* W1 = (const float*)d_in[10];
  const float* b1 = (const float*)d_in[11];
  const float* W2 = (const float*)d_in[12];
  const float* b2 = (const float*)d_in[13];
  const float* g1 = (const float*)d_in[14];
  const float* be1= (const float*)d_in[15];
  const float* g2 = (const float*)d_in[16];
  const float* be2= (const float*)d_in[17];
  const int* mask = (const int*)d_in[18];
  float* out = (float*)d_out;

  char* wsb = (char*)d_ws;
  ushort* xb = (ushort*)wsb;                    // region A: LN1 out -> ao -> prb
  ushort* ao = (ushort*)wsb;
  ushort* prb = (ushort*)wsb;                   // pr bf16, in-place over ao
  ushort* qt = (ushort*)(wsb + 33554432);       // region B: q_t -> yb
  ushort* yb = qt;
  ushort* kt = (ushort*)(wsb + 67108864);       // region C: k_t, v_t -> hb
  ushort* vt = (ushort*)(wsb + 100663296);
  ushort* hb = kt;
  char* d0 = wsb + 134217728;                   // region D: weights/bias
  ushort* Wqkvb = (ushort*)d0;
  ushort* Wob   = (ushort*)(d0 + 393216);
  ushort* W1b   = (ushort*)(d0 + 524288);
  ushort* W2b   = (ushort*)(d0 + 786432);
  float*  bqkv  = (float*)(d0 + 1048576);
  float*  bM4   = (float*)(d0 + 1052672);

  // 0. prep
  prep_k<<<dim3(1025), 256, 0, stream>>>(Wq, Wk, Wv, Wo, W1, W2, bq, bk, bv,
                                         pair_bias, mask, Wqkvb, Wob, W1b, W2b, bqkv, bM4);
  // 1. x = LN1(pair_repr) -> xb (j-major rows)
  ln_k<true><<<dim3(M_/4), 256, 0, stream>>>(pair_repr, g1, be1, xb);
  // 2. qkv projection -> head-major qt/kt/vt (128x256 tile)
  gemm6<true,false,false,true><<<dim3(1536), 512, 0, stream>>>(
      xb, Wqkvb, bqkv, nullptr, (void*)qt, 768, C_, C_, 0, 3);
  // 3. attention -> ao (region A; xb dead)
  attn10<<<dim3(L_*H_), 256, 0, stream>>>(qt, kt, vt, bM4, ao);
  // 4+5. pr(bf16) = ao@Wo.T + bo + pair_repr -> prb (in-place); y = LN2 -> yb
  wo_ln_k<<<dim3(512), 512, 0, stream>>>(ao, Wob, bo, pair_repr, prb, g2, be2, yb);
  // 6. h = relu(y@W1.T + b1) -> hb (128x256 tile)
  gemm6<true,true,false,false><<<dim3(1024), 512, 0, stream>>>(
      yb, W1b, b1, nullptr, (void*)hb, F_, C_, C_, F_, 2);
  // 7. out = prb + h@W2.T + b2 -> d_out (128x256 tile, fp32 + bf16 residual)
  gemm6<false,false,true,false><<<dim3(512), 512, 0, stream>>>(
      hb, W2b, b2, prb, out, C_, F_, F_, C_, 1);
}